// Round 1
// baseline (1412.157 us; speedup 1.0000x reference)
//
#include <hip/hip_runtime.h>
#include <stdint.h>

// ---------------------------------------------------------------------------
// Gemma4 MoE block on gfx950. FP16 MFMA (16x16x32) GEMMs, f32 accumulation.
// Structure: weight transpose->f16, fused norm+router, m97-style 128x128 GEMM
// with global_load_lds staging, gelu*mul elementwise, rms-norm epilogues.
// ---------------------------------------------------------------------------

typedef unsigned short u16;
typedef u16 u16x4 __attribute__((ext_vector_type(4)));
typedef u16 u16x8 __attribute__((ext_vector_type(8)));
typedef _Float16 f16x8 __attribute__((ext_vector_type(8)));
typedef float f32x4 __attribute__((ext_vector_type(4)));
typedef __attribute__((address_space(1))) void* as1_vp;
typedef __attribute__((address_space(3))) void* as3_vp;

#define T_TOK 4096
#define DIM   1024
#define FDIM  2048
#define MDIM  1024
#define NEXP  8

__device__ __forceinline__ u16 f2h(float f) {
  _Float16 h = (_Float16)f;
  return __builtin_bit_cast(u16, h);
}
__device__ __forceinline__ float h2f(u16 u) {
  return (float)__builtin_bit_cast(_Float16, u);
}
__device__ __forceinline__ float gelu_f(float x) {
  // jax.nn.gelu(approximate=True): 0.5x(1+tanh(sqrt(2/pi)(x+0.044715x^3)))
  float t = tanhf(0.7978845608028654f * (x + 0.044715f * x * x * x));
  return 0.5f * x * (1.0f + t);
}
__device__ __forceinline__ void async_copy16(const void* g, void* l) {
  // global -> LDS direct copy, 16B per lane; LDS dest is wave-uniform base +
  // lane*16 (our per-lane lds addr equals exactly that: tid-linear layout).
  __builtin_amdgcn_global_load_lds((as1_vp)(uintptr_t)g,
                                   (as3_vp)(uint32_t)(uintptr_t)l, 16, 0, 0);
}
__device__ __forceinline__ f16x8 lds_frag(const u16* p) {
  return __builtin_bit_cast(f16x8, *(const u16x8*)p);
}

// ---------------------------------------------------------------------------
// GEMM: C[M,N] = A[M,K] @ B[K,N], with A row-major f16 and Bt = B^T ([N,K]).
// 128x128 tile, BK=32, 256 threads = 4 waves (2x2 of 64x64), 16x16x32 MFMA.
// M % 128 == 0, N % 128 == 0, K % 32 == 0 assumed (true for all our shapes).
// EPI: 0 = store f32; 1 = store f16; 2 = C f32 = rowscale[row*8]*acc;
//      3 = C f32 += rowscale[row*8]*acc. (rowscale stride 8 = combine[T,8].)
// ---------------------------------------------------------------------------
template <int EPI>
__global__ __launch_bounds__(256) void gemm_bt(
    const u16* __restrict__ A, const u16* __restrict__ Bt, void* __restrict__ Cv,
    const float* __restrict__ rowscale, int N, int K, long strideB, long strideC) {
  __shared__ __align__(16) u16 As[128 * 32];
  __shared__ __align__(16) u16 Bs[128 * 32];
  const int tid = threadIdx.x;
  const int lane = tid & 63;
  const int wave = tid >> 6;
  const long bm = (long)blockIdx.y * 128;
  const long bn = (long)blockIdx.x * 128;
  const int wm = (wave >> 1) * 64;
  const int wn = (wave & 1) * 64;
  const int z = blockIdx.z;
  Bt += (long)z * strideB;

  f32x4 acc[4][4] = {};

  // staging: 512 16B-chunks per tile; thread handles chunks tid and tid+256.
  const int c0 = tid, c1 = tid + 256;
  const u16* Ag0 = A + (bm + (c0 >> 2)) * (long)K + (c0 & 3) * 8;
  const u16* Ag1 = A + (bm + (c1 >> 2)) * (long)K + (c1 & 3) * 8;
  const u16* Bg0 = Bt + (bn + (c0 >> 2)) * (long)K + (c0 & 3) * 8;
  const u16* Bg1 = Bt + (bn + (c1 >> 2)) * (long)K + (c1 & 3) * 8;
  u16* As0 = &As[c0 * 8];
  u16* As1 = &As[c1 * 8];
  u16* Bs0 = &Bs[c0 * 8];
  u16* Bs1 = &Bs[c1 * 8];

  const int fr = lane & 15;        // row within 16x16 tile (A m / B n)
  const int fk = (lane >> 4) * 8;  // k offset of the 8-elem fragment

  for (int k0 = 0; k0 < K; k0 += 32) {
    async_copy16(Ag0 + k0, As0);
    async_copy16(Ag1 + k0, As1);
    async_copy16(Bg0 + k0, Bs0);
    async_copy16(Bg1 + k0, Bs1);
    __syncthreads();  // compiler emits vmcnt(0) drain before s_barrier
    f16x8 af[4], bq[4];
#pragma unroll
    for (int i = 0; i < 4; i++) af[i] = lds_frag(&As[(wm + i * 16 + fr) * 32 + fk]);
#pragma unroll
    for (int i = 0; i < 4; i++) bq[i] = lds_frag(&Bs[(wn + i * 16 + fr) * 32 + fk]);
#pragma unroll
    for (int mi = 0; mi < 4; mi++)
#pragma unroll
      for (int ni = 0; ni < 4; ni++)
        acc[mi][ni] = __builtin_amdgcn_mfma_f32_16x16x32_f16(af[mi], bq[ni], acc[mi][ni], 0, 0, 0);
    __syncthreads();
  }

  // C/D layout: col = lane&15, row = (lane>>4)*4 + reg (verified m89/m91)
  const int er = (lane >> 4) * 4;
  const int ec = lane & 15;
  float* Cf = (float*)Cv + (long)z * strideC;
  u16* Ch = (u16*)Cv + (long)z * strideC;
#pragma unroll
  for (int mi = 0; mi < 4; mi++) {
#pragma unroll
    for (int r = 0; r < 4; r++) {
      const long row = bm + wm + mi * 16 + er + r;
      float rs = 0.0f;
      if (EPI >= 2) rs = rowscale[row * 8];
#pragma unroll
      for (int ni = 0; ni < 4; ni++) {
        const long col = bn + wn + ni * 16 + ec;
        const float v = acc[mi][ni][r];
        if (EPI == 0)
          Cf[row * N + col] = v;
        else if (EPI == 1)
          Ch[row * N + col] = f2h(v);
        else if (EPI == 2)
          Cf[row * N + col] = rs * v;
        else
          Cf[row * N + col] += rs * v;
      }
    }
  }
}

// ---------------------------------------------------------------------------
// Transpose f32 [R,C] -> f16 [C,R] (batched over blockIdx.z, stride R*C).
// ---------------------------------------------------------------------------
__global__ __launch_bounds__(256) void transpose_cvt(const float* __restrict__ src,
                                                     u16* __restrict__ dst, int R, int C) {
  __shared__ float tile[32][33];
  const long boff = (long)blockIdx.z * R * C;
  src += boff;
  dst += boff;
  const int c0 = blockIdx.x * 32, r0 = blockIdx.y * 32;
  const int tx = threadIdx.x & 31, ty = threadIdx.x >> 5;
#pragma unroll
  for (int i = 0; i < 32; i += 8) tile[ty + i][tx] = src[(long)(r0 + ty + i) * C + c0 + tx];
  __syncthreads();
#pragma unroll
  for (int i = 0; i < 32; i += 8) dst[(long)(c0 + ty + i) * R + r0 + tx] = f2h(tile[tx][ty + i]);
}

__global__ __launch_bounds__(256) void cvt_f16(const float* __restrict__ s,
                                               u16* __restrict__ d, int n) {
  const int i = (blockIdx.x * 256 + threadIdx.x) * 4;
  if (i < n) {
    const float4 v = *(const float4*)(s + i);
    u16x4 o = {f2h(v.x), f2h(v.y), f2h(v.z), f2h(v.w)};
    *(u16x4*)(d + i) = o;
  }
}

// h0 <- gelu(h0) * h1, f16 in place
__global__ __launch_bounds__(256) void gelu_mul(u16* __restrict__ h0,
                                                const u16* __restrict__ h1, long n) {
  const long i = ((long)blockIdx.x * 256 + threadIdx.x) * 8;
  if (i < n) {
    u16x8 a = *(const u16x8*)(h0 + i);
    u16x8 b = *(const u16x8*)(h1 + i);
    u16x8 o;
#pragma unroll
    for (int j = 0; j < 8; j++) o[j] = f2h(gelu_f(h2f(a[j])) * h2f(b[j]));
    *(u16x8*)(h0 + i) = o;
  }
}

// ---------------------------------------------------------------------------
// Fused: routed_in = rms_norm(orig, ln2s) (f16); router logits/softmax/top2;
// combine weights [T,8]; stats[0..7]=top2 counts, stats[8..15]=prob sums.
// One block per token, 256 threads x 4 elems.
// ---------------------------------------------------------------------------
__global__ __launch_bounds__(256) void router_kernel(
    const float* __restrict__ orig, const float* __restrict__ pfs,
    const float* __restrict__ ln2s, const float* __restrict__ rw,
    u16* __restrict__ routed_in, float* __restrict__ combine, float* __restrict__ stats) {
  const int t = blockIdx.x;
  const int tid = threadIdx.x;
  const float* x = orig + (long)t * DIM;
  const int d = tid * 4;
  const float4 v = *(const float4*)(x + d);
  float ss = v.x * v.x + v.y * v.y + v.z * v.z + v.w * v.w;
#pragma unroll
  for (int off = 32; off > 0; off >>= 1) ss += __shfl_down(ss, off);
  __shared__ float red[4];
  __shared__ float lred[4][8];
  if ((tid & 63) == 0) red[tid >> 6] = ss;
  __syncthreads();
  const float rs = rsqrtf((red[0] + red[1] + red[2] + red[3]) * (1.0f / DIM) + 1e-6f);

  const float4 l2 = *(const float4*)(ln2s + d);
  u16x4 ro = {f2h(v.x * rs * l2.x), f2h(v.y * rs * l2.y), f2h(v.z * rs * l2.z),
              f2h(v.w * rs * l2.w)};
  *(u16x4*)(routed_in + (long)t * DIM + d) = ro;

  const float4 pf = *(const float4*)(pfs + d);
  const float c = rs * 0.03125f;  // D^-0.5 = 1/32
  const float g0 = v.x * c * pf.x, g1 = v.y * c * pf.y;
  const float g2 = v.z * c * pf.z, g3 = v.w * c * pf.w;
  float lg[8];
#pragma unroll
  for (int e = 0; e < 8; e++)
    lg[e] = g0 * rw[(d + 0) * 8 + e] + g1 * rw[(d + 1) * 8 + e] +
            g2 * rw[(d + 2) * 8 + e] + g3 * rw[(d + 3) * 8 + e];
#pragma unroll
  for (int e = 0; e < 8; e++)
#pragma unroll
    for (int off = 32; off > 0; off >>= 1) lg[e] += __shfl_down(lg[e], off);
  if ((tid & 63) == 0)
#pragma unroll
    for (int e = 0; e < 8; e++) lred[tid >> 6][e] = lg[e];
  __syncthreads();
  if (tid == 0) {
    float lz[8], p[8];
    float mx = -1e30f;
#pragma unroll
    for (int e = 0; e < 8; e++) {
      lz[e] = lred[0][e] + lred[1][e] + lred[2][e] + lred[3][e];
      mx = fmaxf(mx, lz[e]);
    }
    float s = 0.0f;
#pragma unroll
    for (int e = 0; e < 8; e++) {
      p[e] = expf(lz[e] - mx);
      s += p[e];
    }
    const float invs = 1.0f / s;
#pragma unroll
    for (int e = 0; e < 8; e++) p[e] *= invs;
    int i1 = 0;
    for (int e = 1; e < 8; e++)
      if (p[e] > p[i1]) i1 = e;  // strict > keeps lowest index (lax.top_k)
    int i2 = (i1 == 0) ? 1 : 0;
    for (int e = 0; e < 8; e++)
      if (e != i1 && p[e] > p[i2]) i2 = e;
    const float wsum = p[i1] + p[i2];
    float cb[8] = {0, 0, 0, 0, 0, 0, 0, 0};
    cb[i1] = p[i1] / wsum;
    cb[i2] = p[i2] / wsum;
    float* crow = combine + (long)t * 8;
    for (int e = 0; e < 8; e++) crow[e] = cb[e];
    atomicAdd(&stats[i1], 1.0f);
    atomicAdd(&stats[i2], 1.0f);
    for (int e = 0; e < 8; e++) atomicAdd(&stats[8 + e], p[e]);
  }
}

// out = rms_norm(x, scale)  (ADD=0: write; ADD=1: out += norm)
template <int ADD>
__global__ __launch_bounds__(256) void rms_norm_out(const float* __restrict__ x,
                                                    const float* __restrict__ scale,
                                                    float* __restrict__ out) {
  const int t = blockIdx.x;
  const int tid = threadIdx.x;
  const long base = (long)t * DIM + tid * 4;
  const float4 v = *(const float4*)(x + base);
  float ss = v.x * v.x + v.y * v.y + v.z * v.z + v.w * v.w;
#pragma unroll
  for (int off = 32; off > 0; off >>= 1) ss += __shfl_down(ss, off);
  __shared__ float red[4];
  if ((tid & 63) == 0) red[tid >> 6] = ss;
  __syncthreads();
  const float rs = rsqrtf((red[0] + red[1] + red[2] + red[3]) * (1.0f / DIM) + 1e-6f);
  const float4 sc = *(const float4*)(scale + tid * 4);
  float4 o;
  o.x = v.x * rs * sc.x;
  o.y = v.y * rs * sc.y;
  o.z = v.z * rs * sc.z;
  o.w = v.w * rs * sc.w;
  if (ADD) {
    const float4 prev = *(const float4*)(out + base);
    o.x += prev.x;
    o.y += prev.y;
    o.z += prev.z;
    o.w += prev.w;
  }
  *(float4*)(out + base) = o;
}

__global__ void lb_kernel(const float* __restrict__ stats, float* __restrict__ out) {
  if (threadIdx.x == 0 && blockIdx.x == 0) {
    float s = 0.0f;
    for (int e = 0; e < 8; e++)
      s += (stats[e] / (4096.0f * 2.0f)) * (stats[8 + e] / 4096.0f);
    out[0] = 8.0f * s;
  }
}

// ---------------------------------------------------------------------------
extern "C" void kernel_launch(void* const* d_in, const int* in_sizes, int n_in,
                              void* d_out, int out_size, void* d_ws, size_t ws_size,
                              hipStream_t stream) {
  (void)in_sizes; (void)n_in; (void)out_size;
  const float* inputs   = (const float*)d_in[0];
  const float* orig     = (const float*)d_in[1];
  const float* pfs      = (const float*)d_in[2];
  const float* ln2s     = (const float*)d_in[3];
  const float* post1    = (const float*)d_in[4];
  const float* post2    = (const float*)d_in[5];
  const float* router_w = (const float*)d_in[6];
  const float* e_wi0    = (const float*)d_in[7];
  const float* e_wi1    = (const float*)d_in[8];
  const float* e_wo     = (const float*)d_in[9];
  const float* s_wi0    = (const float*)d_in[10];
  const float* s_wi1    = (const float*)d_in[11];
  const float* s_wo     = (const float*)d_in[12];

  char* ws = (char*)d_ws;
  size_t o = 0;
  auto alloc = [&](size_t bytes) -> void* {
    void* p = ws + o;
    o += (bytes + 255) & ~(size_t)255;
    return p;
  };
  u16* s_wi0_t  = (u16*)alloc((size_t)FDIM * DIM * 2);   // [F,D]
  u16* s_wi1_t  = (u16*)alloc((size_t)FDIM * DIM * 2);   // [F,D]
  u16* s_wo_t   = (u16*)alloc((size_t)DIM * FDIM * 2);   // [D,F]
  u16* e_wi0_t  = (u16*)alloc((size_t)NEXP * MDIM * DIM * 2);  // [E,M,D]
  u16* e_wi1_t  = (u16*)alloc((size_t)NEXP * MDIM * DIM * 2);  // [E,M,D]
  u16* e_wo_t   = (u16*)alloc((size_t)NEXP * DIM * MDIM * 2);  // [E,D,M]
  u16* x_sh     = (u16*)alloc((size_t)T_TOK * DIM * 2);        // inputs f16
  u16* routed   = (u16*)alloc((size_t)T_TOK * DIM * 2);        // normed f16
  float* combine = (float*)alloc((size_t)T_TOK * 8 * 4);       // [T,8]
  float* stats   = (float*)alloc(256);                         // cnt[8], psum[8]
  float* racc    = (float*)alloc((size_t)T_TOK * DIM * 4);     // shared_raw / routed acc
  const size_t h_small = (size_t)T_TOK * FDIM * 2;             // 16 MB
  const size_t h_big   = (size_t)NEXP * T_TOK * MDIM * 2;      // 64 MB
  const bool big = (ws_size > o) && ((ws_size - o) >= 2 * h_big);
  const size_t hb = big ? h_big : h_small;
  u16* H0 = (u16*)alloc(hb);
  u16* H1 = (u16*)alloc(hb);

  hipMemsetAsync(stats, 0, 64, stream);

  // ---- weight transposes (f32 -> f16 B^T layouts) ----
  transpose_cvt<<<dim3(FDIM / 32, DIM / 32, 1), 256, 0, stream>>>(s_wi0, s_wi0_t, DIM, FDIM);
  transpose_cvt<<<dim3(FDIM / 32, DIM / 32, 1), 256, 0, stream>>>(s_wi1, s_wi1_t, DIM, FDIM);
  transpose_cvt<<<dim3(DIM / 32, FDIM / 32, 1), 256, 0, stream>>>(s_wo, s_wo_t, FDIM, DIM);
  transpose_cvt<<<dim3(MDIM / 32, DIM / 32, NEXP), 256, 0, stream>>>(e_wi0, e_wi0_t, DIM, MDIM);
  transpose_cvt<<<dim3(MDIM / 32, DIM / 32, NEXP), 256, 0, stream>>>(e_wi1, e_wi1_t, DIM, MDIM);
  transpose_cvt<<<dim3(DIM / 32, MDIM / 32, NEXP), 256, 0, stream>>>(e_wo, e_wo_t, MDIM, DIM);

  cvt_f16<<<T_TOK * DIM / 4 / 256, 256, 0, stream>>>(inputs, x_sh, T_TOK * DIM);
  router_kernel<<<T_TOK, 256, 0, stream>>>(orig, pfs, ln2s, router_w, routed, combine, stats);

  // ---- shared expert path ----
  gemm_bt<1><<<dim3(FDIM / 128, T_TOK / 128, 1), 256, 0, stream>>>(
      x_sh, s_wi0_t, H0, nullptr, FDIM, DIM, 0, 0);
  gemm_bt<1><<<dim3(FDIM / 128, T_TOK / 128, 1), 256, 0, stream>>>(
      x_sh, s_wi1_t, H1, nullptr, FDIM, DIM, 0, 0);
  gelu_mul<<<(int)((long)T_TOK * FDIM / 8 / 256), 256, 0, stream>>>(H0, H1, (long)T_TOK * FDIM);
  gemm_bt<0><<<dim3(DIM / 128, T_TOK / 128, 1), 256, 0, stream>>>(
      H0, s_wo_t, racc, nullptr, DIM, FDIM, 0, 0);
  rms_norm_out<0><<<T_TOK, 256, 0, stream>>>(racc, post1, (float*)d_out);

  // ---- routed experts (dense, weighted by combine) ----
  if (big) {
    gemm_bt<1><<<dim3(MDIM / 128, T_TOK / 128, NEXP), 256, 0, stream>>>(
        routed, e_wi0_t, H0, nullptr, MDIM, DIM, (long)MDIM * DIM, (long)T_TOK * MDIM);
    gemm_bt<1><<<dim3(MDIM / 128, T_TOK / 128, NEXP), 256, 0, stream>>>(
        routed, e_wi1_t, H1, nullptr, MDIM, DIM, (long)MDIM * DIM, (long)T_TOK * MDIM);
    gelu_mul<<<(int)((long)NEXP * T_TOK * MDIM / 8 / 256), 256, 0, stream>>>(
        H0, H1, (long)NEXP * T_TOK * MDIM);
    for (int e = 0; e < NEXP; e++) {
      if (e == 0)
        gemm_bt<2><<<dim3(DIM / 128, T_TOK / 128, 1), 256, 0, stream>>>(
            H0 + (long)e * T_TOK * MDIM, e_wo_t + (long)e * DIM * MDIM, racc,
            combine + e, DIM, MDIM, 0, 0);
      else
        gemm_bt<3><<<dim3(DIM / 128, T_TOK / 128, 1), 256, 0, stream>>>(
            H0 + (long)e * T_TOK * MDIM, e_wo_t + (long)e * DIM * MDIM, racc,
            combine + e, DIM, MDIM, 0, 0);
    }
  } else {
    for (int e = 0; e < NEXP; e++) {
      gemm_bt<1><<<dim3(MDIM / 128, T_TOK / 128, 1), 256, 0, stream>>>(
          routed, e_wi0_t + (long)e * MDIM * DIM, H0, nullptr, MDIM, DIM, 0, 0);
      gemm_bt<1><<<dim3(MDIM / 128, T_TOK / 128, 1), 256, 0, stream>>>(
          routed, e_wi1_t + (long)e * MDIM * DIM, H1, nullptr, MDIM, DIM, 0, 0);
      gelu_mul<<<(int)((long)T_TOK * MDIM / 8 / 256), 256, 0, stream>>>(
          H0, H1, (long)T_TOK * MDIM);
      if (e == 0)
        gemm_bt<2><<<dim3(DIM / 128, T_TOK / 128, 1), 256, 0, stream>>>(
            H0, e_wo_t + (long)e * DIM * MDIM, racc, combine + e, DIM, MDIM, 0, 0);
      else
        gemm_bt<3><<<dim3(DIM / 128, T_TOK / 128, 1), 256, 0, stream>>>(
            H0, e_wo_t + (long)e * DIM * MDIM, racc, combine + e, DIM, MDIM, 0, 0);
    }
  }

  rms_norm_out<1><<<T_TOK, 256, 0, stream>>>(racc, post2, (float*)d_out);
  lb_kernel<<<1, 64, 0, stream>>>(stats, (float*)d_out + (size_t)T_TOK * DIM);
}

// Round 2
// 904.353 us; speedup vs baseline: 1.5615x; 1.5615x over previous
//
#include <hip/hip_runtime.h>
#include <stdint.h>

// ---------------------------------------------------------------------------
// Gemma4 MoE block on gfx950. FP16 MFMA (16x16x32) GEMMs, f32 accumulation.
// R1: removed router stats atomics (529us of same-line atomic serialization);
// router now writes probs[T,8]; single-block lb_reduce computes the aux loss.
// ---------------------------------------------------------------------------

typedef unsigned short u16;
typedef u16 u16x4 __attribute__((ext_vector_type(4)));
typedef u16 u16x8 __attribute__((ext_vector_type(8)));
typedef _Float16 f16x8 __attribute__((ext_vector_type(8)));
typedef float f32x4 __attribute__((ext_vector_type(4)));
typedef __attribute__((address_space(1))) void* as1_vp;
typedef __attribute__((address_space(3))) void* as3_vp;

#define T_TOK 4096
#define DIM   1024
#define FDIM  2048
#define MDIM  1024
#define NEXP  8

__device__ __forceinline__ u16 f2h(float f) {
  _Float16 h = (_Float16)f;
  return __builtin_bit_cast(u16, h);
}
__device__ __forceinline__ float h2f(u16 u) {
  return (float)__builtin_bit_cast(_Float16, u);
}
__device__ __forceinline__ float gelu_f(float x) {
  // jax.nn.gelu(approximate=True): 0.5x(1+tanh(sqrt(2/pi)(x+0.044715x^3)))
  float t = tanhf(0.7978845608028654f * (x + 0.044715f * x * x * x));
  return 0.5f * x * (1.0f + t);
}
__device__ __forceinline__ void async_copy16(const void* g, void* l) {
  __builtin_amdgcn_global_load_lds((as1_vp)(uintptr_t)g,
                                   (as3_vp)(uint32_t)(uintptr_t)l, 16, 0, 0);
}
__device__ __forceinline__ f16x8 lds_frag(const u16* p) {
  return __builtin_bit_cast(f16x8, *(const u16x8*)p);
}

// ---------------------------------------------------------------------------
// GEMM: C[M,N] = A[M,K] @ B[K,N], with A row-major f16 and Bt = B^T ([N,K]).
// 128x128 tile, BK=32, 256 threads = 4 waves (2x2 of 64x64), 16x16x32 MFMA.
// M % 128 == 0, N % 128 == 0, K % 32 == 0 assumed (true for all our shapes).
// EPI: 0 = store f32; 1 = store f16; 2 = C f32 = rowscale[row*8]*acc;
//      3 = C f32 += rowscale[row*8]*acc. (rowscale stride 8 = combine[T,8].)
// ---------------------------------------------------------------------------
template <int EPI>
__global__ __launch_bounds__(256) void gemm_bt(
    const u16* __restrict__ A, const u16* __restrict__ Bt, void* __restrict__ Cv,
    const float* __restrict__ rowscale, int N, int K, long strideB, long strideC) {
  __shared__ __align__(16) u16 As[128 * 32];
  __shared__ __align__(16) u16 Bs[128 * 32];
  const int tid = threadIdx.x;
  const int lane = tid & 63;
  const int wave = tid >> 6;
  const long bm = (long)blockIdx.y * 128;
  const long bn = (long)blockIdx.x * 128;
  const int wm = (wave >> 1) * 64;
  const int wn = (wave & 1) * 64;
  const int z = blockIdx.z;
  Bt += (long)z * strideB;

  f32x4 acc[4][4] = {};

  const int c0 = tid, c1 = tid + 256;
  const u16* Ag0 = A + (bm + (c0 >> 2)) * (long)K + (c0 & 3) * 8;
  const u16* Ag1 = A + (bm + (c1 >> 2)) * (long)K + (c1 & 3) * 8;
  const u16* Bg0 = Bt + (bn + (c0 >> 2)) * (long)K + (c0 & 3) * 8;
  const u16* Bg1 = Bt + (bn + (c1 >> 2)) * (long)K + (c1 & 3) * 8;
  u16* As0 = &As[c0 * 8];
  u16* As1 = &As[c1 * 8];
  u16* Bs0 = &Bs[c0 * 8];
  u16* Bs1 = &Bs[c1 * 8];

  const int fr = lane & 15;        // row within 16x16 tile (A m / B n)
  const int fk = (lane >> 4) * 8;  // k offset of the 8-elem fragment

  for (int k0 = 0; k0 < K; k0 += 32) {
    async_copy16(Ag0 + k0, As0);
    async_copy16(Ag1 + k0, As1);
    async_copy16(Bg0 + k0, Bs0);
    async_copy16(Bg1 + k0, Bs1);
    __syncthreads();
    f16x8 af[4], bq[4];
#pragma unroll
    for (int i = 0; i < 4; i++) af[i] = lds_frag(&As[(wm + i * 16 + fr) * 32 + fk]);
#pragma unroll
    for (int i = 0; i < 4; i++) bq[i] = lds_frag(&Bs[(wn + i * 16 + fr) * 32 + fk]);
#pragma unroll
    for (int mi = 0; mi < 4; mi++)
#pragma unroll
      for (int ni = 0; ni < 4; ni++)
        acc[mi][ni] = __builtin_amdgcn_mfma_f32_16x16x32_f16(af[mi], bq[ni], acc[mi][ni], 0, 0, 0);
    __syncthreads();
  }

  // C/D layout: col = lane&15, row = (lane>>4)*4 + reg (verified m89/m91)
  const int er = (lane >> 4) * 4;
  const int ec = lane & 15;
  float* Cf = (float*)Cv + (long)z * strideC;
  u16* Ch = (u16*)Cv + (long)z * strideC;
#pragma unroll
  for (int mi = 0; mi < 4; mi++) {
#pragma unroll
    for (int r = 0; r < 4; r++) {
      const long row = bm + wm + mi * 16 + er + r;
      float rs = 0.0f;
      if (EPI >= 2) rs = rowscale[row * 8];
#pragma unroll
      for (int ni = 0; ni < 4; ni++) {
        const long col = bn + wn + ni * 16 + ec;
        const float v = acc[mi][ni][r];
        if (EPI == 0)
          Cf[row * N + col] = v;
        else if (EPI == 1)
          Ch[row * N + col] = f2h(v);
        else if (EPI == 2)
          Cf[row * N + col] = rs * v;
        else
          Cf[row * N + col] += rs * v;
      }
    }
  }
}

// ---------------------------------------------------------------------------
// Transpose f32 [R,C] -> f16 [C,R] (batched over blockIdx.z, stride R*C).
// ---------------------------------------------------------------------------
__global__ __launch_bounds__(256) void transpose_cvt(const float* __restrict__ src,
                                                     u16* __restrict__ dst, int R, int C) {
  __shared__ float tile[32][33];
  const long boff = (long)blockIdx.z * R * C;
  src += boff;
  dst += boff;
  const int c0 = blockIdx.x * 32, r0 = blockIdx.y * 32;
  const int tx = threadIdx.x & 31, ty = threadIdx.x >> 5;
#pragma unroll
  for (int i = 0; i < 32; i += 8) tile[ty + i][tx] = src[(long)(r0 + ty + i) * C + c0 + tx];
  __syncthreads();
#pragma unroll
  for (int i = 0; i < 32; i += 8) dst[(long)(c0 + ty + i) * R + r0 + tx] = f2h(tile[tx][ty + i]);
}

__global__ __launch_bounds__(256) void cvt_f16(const float* __restrict__ s,
                                               u16* __restrict__ d, int n) {
  const int i = (blockIdx.x * 256 + threadIdx.x) * 4;
  if (i < n) {
    const float4 v = *(const float4*)(s + i);
    u16x4 o = {f2h(v.x), f2h(v.y), f2h(v.z), f2h(v.w)};
    *(u16x4*)(d + i) = o;
  }
}

// h0 <- gelu(h0) * h1, f16 in place
__global__ __launch_bounds__(256) void gelu_mul(u16* __restrict__ h0,
                                                const u16* __restrict__ h1, long n) {
  const long i = ((long)blockIdx.x * 256 + threadIdx.x) * 8;
  if (i < n) {
    u16x8 a = *(const u16x8*)(h0 + i);
    u16x8 b = *(const u16x8*)(h1 + i);
    u16x8 o;
#pragma unroll
    for (int j = 0; j < 8; j++) o[j] = f2h(gelu_f(h2f(a[j])) * h2f(b[j]));
    *(u16x8*)(h0 + i) = o;
  }
}

// ---------------------------------------------------------------------------
// Fused: routed_in = rms_norm(orig, ln2s) (f16); router logits/softmax/top2;
// combine weights [T,8]; probs [T,8] (full softmax, for the aux loss).
// One block per token, 256 threads x 4 elems. NO atomics.
// ---------------------------------------------------------------------------
__global__ __launch_bounds__(256) void router_kernel(
    const float* __restrict__ orig, const float* __restrict__ pfs,
    const float* __restrict__ ln2s, const float* __restrict__ rw,
    u16* __restrict__ routed_in, float* __restrict__ combine,
    float* __restrict__ probs_out) {
  const int t = blockIdx.x;
  const int tid = threadIdx.x;
  const float* x = orig + (long)t * DIM;
  const int d = tid * 4;
  const float4 v = *(const float4*)(x + d);
  float ss = v.x * v.x + v.y * v.y + v.z * v.z + v.w * v.w;
#pragma unroll
  for (int off = 32; off > 0; off >>= 1) ss += __shfl_down(ss, off);
  __shared__ float red[4];
  __shared__ float lred[4][8];
  if ((tid & 63) == 0) red[tid >> 6] = ss;
  __syncthreads();
  const float rs = rsqrtf((red[0] + red[1] + red[2] + red[3]) * (1.0f / DIM) + 1e-6f);

  const float4 l2 = *(const float4*)(ln2s + d);
  u16x4 ro = {f2h(v.x * rs * l2.x), f2h(v.y * rs * l2.y), f2h(v.z * rs * l2.z),
              f2h(v.w * rs * l2.w)};
  *(u16x4*)(routed_in + (long)t * DIM + d) = ro;

  const float4 pf = *(const float4*)(pfs + d);
  const float c = rs * 0.03125f;  // D^-0.5 = 1/32
  const float g0 = v.x * c * pf.x, g1 = v.y * c * pf.y;
  const float g2 = v.z * c * pf.z, g3 = v.w * c * pf.w;
  float lg[8];
#pragma unroll
  for (int e = 0; e < 8; e++)
    lg[e] = g0 * rw[(d + 0) * 8 + e] + g1 * rw[(d + 1) * 8 + e] +
            g2 * rw[(d + 2) * 8 + e] + g3 * rw[(d + 3) * 8 + e];
#pragma unroll
  for (int e = 0; e < 8; e++)
#pragma unroll
    for (int off = 32; off > 0; off >>= 1) lg[e] += __shfl_down(lg[e], off);
  if ((tid & 63) == 0)
#pragma unroll
    for (int e = 0; e < 8; e++) lred[tid >> 6][e] = lg[e];
  __syncthreads();
  if (tid == 0) {
    float lz[8], p[8];
    float mx = -1e30f;
#pragma unroll
    for (int e = 0; e < 8; e++) {
      lz[e] = lred[0][e] + lred[1][e] + lred[2][e] + lred[3][e];
      mx = fmaxf(mx, lz[e]);
    }
    float s = 0.0f;
#pragma unroll
    for (int e = 0; e < 8; e++) {
      p[e] = expf(lz[e] - mx);
      s += p[e];
    }
    const float invs = 1.0f / s;
#pragma unroll
    for (int e = 0; e < 8; e++) p[e] *= invs;
    int i1 = 0;
    for (int e = 1; e < 8; e++)
      if (p[e] > p[i1]) i1 = e;  // strict > keeps lowest index (lax.top_k)
    int i2 = (i1 == 0) ? 1 : 0;
    for (int e = 0; e < 8; e++)
      if (e != i1 && p[e] > p[i2]) i2 = e;
    const float wsum = p[i1] + p[i2];
    float cb[8] = {0, 0, 0, 0, 0, 0, 0, 0};
    cb[i1] = p[i1] / wsum;
    cb[i2] = p[i2] / wsum;
    float* crow = combine + (long)t * 8;
    float* prow = probs_out + (long)t * 8;
    for (int e = 0; e < 8; e++) crow[e] = cb[e];
    for (int e = 0; e < 8; e++) prow[e] = p[e];
  }
}

// ---------------------------------------------------------------------------
// Single-block aux-loss reduction: frac_tokens from (combine>0), frac_probs
// from probs sums. 256 threads x 16 tokens. Writes lb_loss to out[0].
// ---------------------------------------------------------------------------
__global__ __launch_bounds__(256) void lb_reduce(const float* __restrict__ probs,
                                                 const float* __restrict__ combine,
                                                 float* __restrict__ out) {
  const int tid = threadIdx.x;
  float psum[8] = {}, cnt[8] = {};
  for (int tt = 0; tt < 16; tt++) {
    const long t = (long)tid * 16 + tt;
    const float4* pp = (const float4*)(probs + t * 8);
    const float4* cc = (const float4*)(combine + t * 8);
    const float4 p0 = pp[0], p1 = pp[1];
    const float4 c0 = cc[0], c1 = cc[1];
    psum[0] += p0.x; psum[1] += p0.y; psum[2] += p0.z; psum[3] += p0.w;
    psum[4] += p1.x; psum[5] += p1.y; psum[6] += p1.z; psum[7] += p1.w;
    cnt[0] += (c0.x > 0.0f); cnt[1] += (c0.y > 0.0f);
    cnt[2] += (c0.z > 0.0f); cnt[3] += (c0.w > 0.0f);
    cnt[4] += (c1.x > 0.0f); cnt[5] += (c1.y > 0.0f);
    cnt[6] += (c1.z > 0.0f); cnt[7] += (c1.w > 0.0f);
  }
#pragma unroll
  for (int e = 0; e < 8; e++)
#pragma unroll
    for (int off = 32; off > 0; off >>= 1) {
      psum[e] += __shfl_down(psum[e], off);
      cnt[e] += __shfl_down(cnt[e], off);
    }
  __shared__ float sp[4][8], sc[4][8];
  if ((tid & 63) == 0)
#pragma unroll
    for (int e = 0; e < 8; e++) {
      sp[tid >> 6][e] = psum[e];
      sc[tid >> 6][e] = cnt[e];
    }
  __syncthreads();
  if (tid == 0) {
    float loss = 0.0f;
#pragma unroll
    for (int e = 0; e < 8; e++) {
      const float fp = (sp[0][e] + sp[1][e] + sp[2][e] + sp[3][e]) / 4096.0f;
      const float ft = (sc[0][e] + sc[1][e] + sc[2][e] + sc[3][e]) / (4096.0f * 2.0f);
      loss += ft * fp;
    }
    out[0] = 8.0f * loss;
  }
}

// out = rms_norm(x, scale)  (ADD=0: write; ADD=1: out += norm)
template <int ADD>
__global__ __launch_bounds__(256) void rms_norm_out(const float* __restrict__ x,
                                                    const float* __restrict__ scale,
                                                    float* __restrict__ out) {
  const int t = blockIdx.x;
  const int tid = threadIdx.x;
  const long base = (long)t * DIM + tid * 4;
  const float4 v = *(const float4*)(x + base);
  float ss = v.x * v.x + v.y * v.y + v.z * v.z + v.w * v.w;
#pragma unroll
  for (int off = 32; off > 0; off >>= 1) ss += __shfl_down(ss, off);
  __shared__ float red[4];
  if ((tid & 63) == 0) red[tid >> 6] = ss;
  __syncthreads();
  const float rs = rsqrtf((red[0] + red[1] + red[2] + red[3]) * (1.0f / DIM) + 1e-6f);
  const float4 sc = *(const float4*)(scale + tid * 4);
  float4 o;
  o.x = v.x * rs * sc.x;
  o.y = v.y * rs * sc.y;
  o.z = v.z * rs * sc.z;
  o.w = v.w * rs * sc.w;
  if (ADD) {
    const float4 prev = *(const float4*)(out + base);
    o.x += prev.x;
    o.y += prev.y;
    o.z += prev.z;
    o.w += prev.w;
  }
  *(float4*)(out + base) = o;
}

// ---------------------------------------------------------------------------
extern "C" void kernel_launch(void* const* d_in, const int* in_sizes, int n_in,
                              void* d_out, int out_size, void* d_ws, size_t ws_size,
                              hipStream_t stream) {
  (void)in_sizes; (void)n_in; (void)out_size;
  const float* inputs   = (const float*)d_in[0];
  const float* orig     = (const float*)d_in[1];
  const float* pfs      = (const float*)d_in[2];
  const float* ln2s     = (const float*)d_in[3];
  const float* post1    = (const float*)d_in[4];
  const float* post2    = (const float*)d_in[5];
  const float* router_w = (const float*)d_in[6];
  const float* e_wi0    = (const float*)d_in[7];
  const float* e_wi1    = (const float*)d_in[8];
  const float* e_wo     = (const float*)d_in[9];
  const float* s_wi0    = (const float*)d_in[10];
  const float* s_wi1    = (const float*)d_in[11];
  const float* s_wo     = (const float*)d_in[12];

  char* ws = (char*)d_ws;
  size_t o = 0;
  auto alloc = [&](size_t bytes) -> void* {
    void* p = ws + o;
    o += (bytes + 255) & ~(size_t)255;
    return p;
  };
  u16* s_wi0_t  = (u16*)alloc((size_t)FDIM * DIM * 2);   // [F,D]
  u16* s_wi1_t  = (u16*)alloc((size_t)FDIM * DIM * 2);   // [F,D]
  u16* s_wo_t   = (u16*)alloc((size_t)DIM * FDIM * 2);   // [D,F]
  u16* e_wi0_t  = (u16*)alloc((size_t)NEXP * MDIM * DIM * 2);  // [E,M,D]
  u16* e_wi1_t  = (u16*)alloc((size_t)NEXP * MDIM * DIM * 2);  // [E,M,D]
  u16* e_wo_t   = (u16*)alloc((size_t)NEXP * DIM * MDIM * 2);  // [E,D,M]
  u16* x_sh     = (u16*)alloc((size_t)T_TOK * DIM * 2);        // inputs f16
  u16* routed   = (u16*)alloc((size_t)T_TOK * DIM * 2);        // normed f16
  float* combine = (float*)alloc((size_t)T_TOK * 8 * 4);       // [T,8]
  float* probs   = (float*)alloc((size_t)T_TOK * 8 * 4);       // [T,8]
  float* racc    = (float*)alloc((size_t)T_TOK * DIM * 4);     // shared_raw / routed acc
  const size_t h_small = (size_t)T_TOK * FDIM * 2;             // 16 MB
  const size_t h_big   = (size_t)NEXP * T_TOK * MDIM * 2;      // 64 MB
  const bool big = (ws_size > o) && ((ws_size - o) >= 2 * h_big);
  const size_t hb = big ? h_big : h_small;
  u16* H0 = (u16*)alloc(hb);
  u16* H1 = (u16*)alloc(hb);

  // ---- weight transposes (f32 -> f16 B^T layouts) ----
  transpose_cvt<<<dim3(FDIM / 32, DIM / 32, 1), 256, 0, stream>>>(s_wi0, s_wi0_t, DIM, FDIM);
  transpose_cvt<<<dim3(FDIM / 32, DIM / 32, 1), 256, 0, stream>>>(s_wi1, s_wi1_t, DIM, FDIM);
  transpose_cvt<<<dim3(DIM / 32, FDIM / 32, 1), 256, 0, stream>>>(s_wo, s_wo_t, FDIM, DIM);
  transpose_cvt<<<dim3(MDIM / 32, DIM / 32, NEXP), 256, 0, stream>>>(e_wi0, e_wi0_t, DIM, MDIM);
  transpose_cvt<<<dim3(MDIM / 32, DIM / 32, NEXP), 256, 0, stream>>>(e_wi1, e_wi1_t, DIM, MDIM);
  transpose_cvt<<<dim3(DIM / 32, MDIM / 32, NEXP), 256, 0, stream>>>(e_wo, e_wo_t, MDIM, DIM);

  cvt_f16<<<T_TOK * DIM / 4 / 256, 256, 0, stream>>>(inputs, x_sh, T_TOK * DIM);
  router_kernel<<<T_TOK, 256, 0, stream>>>(orig, pfs, ln2s, router_w, routed, combine, probs);
  lb_reduce<<<1, 256, 0, stream>>>(probs, combine, (float*)d_out + (size_t)T_TOK * DIM);

  // ---- shared expert path ----
  gemm_bt<1><<<dim3(FDIM / 128, T_TOK / 128, 1), 256, 0, stream>>>(
      x_sh, s_wi0_t, H0, nullptr, FDIM, DIM, 0, 0);
  gemm_bt<1><<<dim3(FDIM / 128, T_TOK / 128, 1), 256, 0, stream>>>(
      x_sh, s_wi1_t, H1, nullptr, FDIM, DIM, 0, 0);
  gelu_mul<<<(int)((long)T_TOK * FDIM / 8 / 256), 256, 0, stream>>>(H0, H1, (long)T_TOK * FDIM);
  gemm_bt<0><<<dim3(DIM / 128, T_TOK / 128, 1), 256, 0, stream>>>(
      H0, s_wo_t, racc, nullptr, DIM, FDIM, 0, 0);
  rms_norm_out<0><<<T_TOK, 256, 0, stream>>>(racc, post1, (float*)d_out);

  // ---- routed experts (dense, weighted by combine) ----
  if (big) {
    gemm_bt<1><<<dim3(MDIM / 128, T_TOK / 128, NEXP), 256, 0, stream>>>(
        routed, e_wi0_t, H0, nullptr, MDIM, DIM, (long)MDIM * DIM, (long)T_TOK * MDIM);
    gemm_bt<1><<<dim3(MDIM / 128, T_TOK / 128, NEXP), 256, 0, stream>>>(
        routed, e_wi1_t, H1, nullptr, MDIM, DIM, (long)MDIM * DIM, (long)T_TOK * MDIM);
    gelu_mul<<<(int)((long)NEXP * T_TOK * MDIM / 8 / 256), 256, 0, stream>>>(
        H0, H1, (long)NEXP * T_TOK * MDIM);
    for (int e = 0; e < NEXP; e++) {
      if (e == 0)
        gemm_bt<2><<<dim3(DIM / 128, T_TOK / 128, 1), 256, 0, stream>>>(
            H0 + (long)e * T_TOK * MDIM, e_wo_t + (long)e * DIM * MDIM, racc,
            combine + e, DIM, MDIM, 0, 0);
      else
        gemm_bt<3><<<dim3(DIM / 128, T_TOK / 128, 1), 256, 0, stream>>>(
            H0 + (long)e * T_TOK * MDIM, e_wo_t + (long)e * DIM * MDIM, racc,
            combine + e, DIM, MDIM, 0, 0);
    }
  } else {
    for (int e = 0; e < NEXP; e++) {
      gemm_bt<1><<<dim3(MDIM / 128, T_TOK / 128, 1), 256, 0, stream>>>(
          routed, e_wi0_t + (long)e * MDIM * DIM, H0, nullptr, MDIM, DIM, 0, 0);
      gemm_bt<1><<<dim3(MDIM / 128, T_TOK / 128, 1), 256, 0, stream>>>(
          routed, e_wi1_t + (long)e * MDIM * DIM, H1, nullptr, MDIM, DIM, 0, 0);
      gelu_mul<<<(int)((long)T_TOK * MDIM / 8 / 256), 256, 0, stream>>>(
          H0, H1, (long)T_TOK * MDIM);
      if (e == 0)
        gemm_bt<2><<<dim3(DIM / 128, T_TOK / 128, 1), 256, 0, stream>>>(
            H0, e_wo_t + (long)e * DIM * MDIM, racc, combine + e, DIM, MDIM, 0, 0);
      else
        gemm_bt<3><<<dim3(DIM / 128, T_TOK / 128, 1), 256, 0, stream>>>(
            H0, e_wo_t + (long)e * DIM * MDIM, racc, combine + e, DIM, MDIM, 0, 0);
    }
  }

  rms_norm_out<1><<<T_TOK, 256, 0, stream>>>(racc, post2, (float*)d_out);
}

// Round 3
// 506.841 us; speedup vs baseline: 2.7862x; 1.7843x over previous
//
#include <hip/hip_runtime.h>
#include <stdint.h>

// ---------------------------------------------------------------------------
// Gemma4 MoE block on gfx950. FP16 MFMA (16x16x32) GEMMs, f32 accumulation.
// R1: atomic-free router + lb_reduce.
// R2: SPARSE top-2 routed experts: count/setup/scatter bucketing (tile-padded,
//     per-expert), gathered grouped in-GEMM, grouped out-GEMM, fused
//     combine+rms-norm by recorded assignment positions. 4x FLOP cut.
// ---------------------------------------------------------------------------

typedef unsigned short u16;
typedef u16 u16x4 __attribute__((ext_vector_type(4)));
typedef u16 u16x8 __attribute__((ext_vector_type(8)));
typedef _Float16 f16x8 __attribute__((ext_vector_type(8)));
typedef float f32x4 __attribute__((ext_vector_type(4)));
typedef __attribute__((address_space(1))) void* as1_vp;
typedef __attribute__((address_space(3))) void* as3_vp;

#define T_TOK 4096
#define DIM   1024
#define FDIM  2048
#define MDIM  1024
#define NEXP  8
#define MAXTILES 72            // sum ceil(cnt_e/128) <= 64 + 7, padded
#define HROWS (MAXTILES * 128) // 9216 padded assignment rows

__device__ __forceinline__ u16 f2h(float f) {
  _Float16 h = (_Float16)f;
  return __builtin_bit_cast(u16, h);
}
__device__ __forceinline__ float h2f(u16 u) {
  return (float)__builtin_bit_cast(_Float16, u);
}
__device__ __forceinline__ float gelu_f(float x) {
  float t = tanhf(0.7978845608028654f * (x + 0.044715f * x * x * x));
  return 0.5f * x * (1.0f + t);
}
__device__ __forceinline__ void async_copy16(const void* g, void* l) {
  __builtin_amdgcn_global_load_lds((as1_vp)(uintptr_t)g,
                                   (as3_vp)(uint32_t)(uintptr_t)l, 16, 0, 0);
}
__device__ __forceinline__ f16x8 lds_frag(const u16* p) {
  return __builtin_bit_cast(f16x8, *(const u16x8*)p);
}

// ---------------------------------------------------------------------------
// Dense GEMM: C[M,N] = A[M,K] @ B[K,N]; A row-major f16, Bt = B^T ([N,K]).
// 128x128 tile, BK=32, 4 waves (2x2 of 64x64). EPI: 0=f32 store, 1=f16 store.
// ---------------------------------------------------------------------------
template <int EPI>
__global__ __launch_bounds__(256) void gemm_bt(
    const u16* __restrict__ A, const u16* __restrict__ Bt, void* __restrict__ Cv,
    int N, int K, long strideB, long strideC) {
  __shared__ __align__(16) u16 As[128 * 32];
  __shared__ __align__(16) u16 Bs[128 * 32];
  const int tid = threadIdx.x;
  const int lane = tid & 63;
  const int wave = tid >> 6;
  const long bm = (long)blockIdx.y * 128;
  const long bn = (long)blockIdx.x * 128;
  const int wm = (wave >> 1) * 64;
  const int wn = (wave & 1) * 64;
  Bt += (long)blockIdx.z * strideB;

  f32x4 acc[4][4] = {};
  const int c0 = tid, c1 = tid + 256;
  const u16* Ag0 = A + (bm + (c0 >> 2)) * (long)K + (c0 & 3) * 8;
  const u16* Ag1 = A + (bm + (c1 >> 2)) * (long)K + (c1 & 3) * 8;
  const u16* Bg0 = Bt + (bn + (c0 >> 2)) * (long)K + (c0 & 3) * 8;
  const u16* Bg1 = Bt + (bn + (c1 >> 2)) * (long)K + (c1 & 3) * 8;
  u16 *As0 = &As[c0 * 8], *As1 = &As[c1 * 8];
  u16 *Bs0 = &Bs[c0 * 8], *Bs1 = &Bs[c1 * 8];
  const int fr = lane & 15;
  const int fk = (lane >> 4) * 8;

  for (int k0 = 0; k0 < K; k0 += 32) {
    async_copy16(Ag0 + k0, As0);
    async_copy16(Ag1 + k0, As1);
    async_copy16(Bg0 + k0, Bs0);
    async_copy16(Bg1 + k0, Bs1);
    __syncthreads();
    f16x8 af[4], bq[4];
#pragma unroll
    for (int i = 0; i < 4; i++) af[i] = lds_frag(&As[(wm + i * 16 + fr) * 32 + fk]);
#pragma unroll
    for (int i = 0; i < 4; i++) bq[i] = lds_frag(&Bs[(wn + i * 16 + fr) * 32 + fk]);
#pragma unroll
    for (int mi = 0; mi < 4; mi++)
#pragma unroll
      for (int ni = 0; ni < 4; ni++)
        acc[mi][ni] = __builtin_amdgcn_mfma_f32_16x16x32_f16(af[mi], bq[ni], acc[mi][ni], 0, 0, 0);
    __syncthreads();
  }

  const int er = (lane >> 4) * 4;  // C/D: col=lane&15, row=(lane>>4)*4+reg
  const int ec = lane & 15;
  float* Cf = (float*)Cv + (long)blockIdx.z * strideC;
  u16* Ch = (u16*)Cv + (long)blockIdx.z * strideC;
#pragma unroll
  for (int mi = 0; mi < 4; mi++)
#pragma unroll
    for (int r = 0; r < 4; r++) {
      const long row = bm + wm + mi * 16 + er + r;
#pragma unroll
      for (int ni = 0; ni < 4; ni++) {
        const long col = bn + wn + ni * 16 + ec;
        const float v = acc[mi][ni][r];
        if (EPI == 0) Cf[row * N + col] = v;
        else          Ch[row * N + col] = f2h(v);
      }
    }
}

// ---------------------------------------------------------------------------
// Grouped MoE GEMM over tile descriptors. GATHER: A-row indirection via ridx.
// C rows are padded assignment positions (prow0 + local row).
// ---------------------------------------------------------------------------
template <int GATHER, int EPI>
__global__ __launch_bounds__(256) void gemm_moe(
    const u16* __restrict__ A, const u16* __restrict__ Bt, void* __restrict__ Cv,
    const int* __restrict__ ridx, const int2* __restrict__ tdesc,
    const int* __restrict__ n_tiles, int N, int K,
    long strideBe, long strideBz, long strideCz) {
  if ((int)blockIdx.y >= *n_tiles) return;
  __shared__ __align__(16) u16 As[128 * 32];
  __shared__ __align__(16) u16 Bs[128 * 32];
  const int2 td = tdesc[blockIdx.y];
  const int e = td.x;
  const long prow0 = td.y;
  const int tid = threadIdx.x;
  const int lane = tid & 63;
  const int wave = tid >> 6;
  const long bn = (long)blockIdx.x * 128;
  const int wm = (wave >> 1) * 64;
  const int wn = (wave & 1) * 64;
  Bt += (long)e * strideBe + (long)blockIdx.z * strideBz;

  f32x4 acc[4][4] = {};
  const int c0 = tid, c1 = tid + 256;
  long arow0, arow1;
  if (GATHER) {
    arow0 = ridx[prow0 + (c0 >> 2)];
    arow1 = ridx[prow0 + (c1 >> 2)];
  } else {
    arow0 = prow0 + (c0 >> 2);
    arow1 = prow0 + (c1 >> 2);
  }
  const u16* Ag0 = A + arow0 * (long)K + (c0 & 3) * 8;
  const u16* Ag1 = A + arow1 * (long)K + (c1 & 3) * 8;
  const u16* Bg0 = Bt + (bn + (c0 >> 2)) * (long)K + (c0 & 3) * 8;
  const u16* Bg1 = Bt + (bn + (c1 >> 2)) * (long)K + (c1 & 3) * 8;
  u16 *As0 = &As[c0 * 8], *As1 = &As[c1 * 8];
  u16 *Bs0 = &Bs[c0 * 8], *Bs1 = &Bs[c1 * 8];
  const int fr = lane & 15;
  const int fk = (lane >> 4) * 8;

  for (int k0 = 0; k0 < K; k0 += 32) {
    async_copy16(Ag0 + k0, As0);
    async_copy16(Ag1 + k0, As1);
    async_copy16(Bg0 + k0, Bs0);
    async_copy16(Bg1 + k0, Bs1);
    __syncthreads();
    f16x8 af[4], bq[4];
#pragma unroll
    for (int i = 0; i < 4; i++) af[i] = lds_frag(&As[(wm + i * 16 + fr) * 32 + fk]);
#pragma unroll
    for (int i = 0; i < 4; i++) bq[i] = lds_frag(&Bs[(wn + i * 16 + fr) * 32 + fk]);
#pragma unroll
    for (int mi = 0; mi < 4; mi++)
#pragma unroll
      for (int ni = 0; ni < 4; ni++)
        acc[mi][ni] = __builtin_amdgcn_mfma_f32_16x16x32_f16(af[mi], bq[ni], acc[mi][ni], 0, 0, 0);
    __syncthreads();
  }

  const int er = (lane >> 4) * 4;
  const int ec = lane & 15;
  float* Cf = (float*)Cv + (long)blockIdx.z * strideCz;
  u16* Ch = (u16*)Cv + (long)blockIdx.z * strideCz;
#pragma unroll
  for (int mi = 0; mi < 4; mi++)
#pragma unroll
    for (int r = 0; r < 4; r++) {
      const long row = prow0 + wm + mi * 16 + er + r;
#pragma unroll
      for (int ni = 0; ni < 4; ni++) {
        const long col = bn + wn + ni * 16 + ec;
        const float v = acc[mi][ni][r];
        if (EPI == 0) Cf[row * N + col] = v;
        else          Ch[row * N + col] = f2h(v);
      }
    }
}

// ---------------------------------------------------------------------------
__global__ __launch_bounds__(256) void transpose_cvt(const float* __restrict__ src,
                                                     u16* __restrict__ dst, int R, int C) {
  __shared__ float tile[32][33];
  const long boff = (long)blockIdx.z * R * C;
  src += boff;
  dst += boff;
  const int c0 = blockIdx.x * 32, r0 = blockIdx.y * 32;
  const int tx = threadIdx.x & 31, ty = threadIdx.x >> 5;
#pragma unroll
  for (int i = 0; i < 32; i += 8) tile[ty + i][tx] = src[(long)(r0 + ty + i) * C + c0 + tx];
  __syncthreads();
#pragma unroll
  for (int i = 0; i < 32; i += 8) dst[(long)(c0 + ty + i) * R + r0 + tx] = f2h(tile[tx][ty + i]);
}

__global__ __launch_bounds__(256) void cvt_f16(const float* __restrict__ s,
                                               u16* __restrict__ d, int n) {
  const int i = (blockIdx.x * 256 + threadIdx.x) * 4;
  if (i < n) {
    const float4 v = *(const float4*)(s + i);
    u16x4 o = {f2h(v.x), f2h(v.y), f2h(v.z), f2h(v.w)};
    *(u16x4*)(d + i) = o;
  }
}

__global__ __launch_bounds__(256) void gelu_mul(u16* __restrict__ h0,
                                                const u16* __restrict__ h1, long n) {
  const long i = ((long)blockIdx.x * 256 + threadIdx.x) * 8;
  if (i < n) {
    u16x8 a = *(const u16x8*)(h0 + i);
    u16x8 b = *(const u16x8*)(h1 + i);
    u16x8 o;
#pragma unroll
    for (int j = 0; j < 8; j++) o[j] = f2h(gelu_f(h2f(a[j])) * h2f(b[j]));
    *(u16x8*)(h0 + i) = o;
  }
}

// ---------------------------------------------------------------------------
// Router: routed_in = rms_norm(orig,ln2s) f16; softmax/top2; writes per-token
// expert ids eidx[2t..], renormalized weights ewt[2t..], probs[T,8]. No atomics.
// ---------------------------------------------------------------------------
__global__ __launch_bounds__(256) void router_kernel(
    const float* __restrict__ orig, const float* __restrict__ pfs,
    const float* __restrict__ ln2s, const float* __restrict__ rw,
    u16* __restrict__ routed_in, int* __restrict__ eidx, float* __restrict__ ewt,
    float* __restrict__ probs_out) {
  const int t = blockIdx.x;
  const int tid = threadIdx.x;
  const float* x = orig + (long)t * DIM;
  const int d = tid * 4;
  const float4 v = *(const float4*)(x + d);
  float ss = v.x * v.x + v.y * v.y + v.z * v.z + v.w * v.w;
#pragma unroll
  for (int off = 32; off > 0; off >>= 1) ss += __shfl_down(ss, off);
  __shared__ float red[4];
  __shared__ float lred[4][8];
  if ((tid & 63) == 0) red[tid >> 6] = ss;
  __syncthreads();
  const float rs = rsqrtf((red[0] + red[1] + red[2] + red[3]) * (1.0f / DIM) + 1e-6f);

  const float4 l2 = *(const float4*)(ln2s + d);
  u16x4 ro = {f2h(v.x * rs * l2.x), f2h(v.y * rs * l2.y), f2h(v.z * rs * l2.z),
              f2h(v.w * rs * l2.w)};
  *(u16x4*)(routed_in + (long)t * DIM + d) = ro;

  const float4 pf = *(const float4*)(pfs + d);
  const float c = rs * 0.03125f;  // D^-0.5
  const float g0 = v.x * c * pf.x, g1 = v.y * c * pf.y;
  const float g2 = v.z * c * pf.z, g3 = v.w * c * pf.w;
  float lg[8];
#pragma unroll
  for (int e = 0; e < 8; e++)
    lg[e] = g0 * rw[(d + 0) * 8 + e] + g1 * rw[(d + 1) * 8 + e] +
            g2 * rw[(d + 2) * 8 + e] + g3 * rw[(d + 3) * 8 + e];
#pragma unroll
  for (int e = 0; e < 8; e++)
#pragma unroll
    for (int off = 32; off > 0; off >>= 1) lg[e] += __shfl_down(lg[e], off);
  if ((tid & 63) == 0)
#pragma unroll
    for (int e = 0; e < 8; e++) lred[tid >> 6][e] = lg[e];
  __syncthreads();
  if (tid == 0) {
    float lz[8], p[8];
    float mx = -1e30f;
#pragma unroll
    for (int e = 0; e < 8; e++) {
      lz[e] = lred[0][e] + lred[1][e] + lred[2][e] + lred[3][e];
      mx = fmaxf(mx, lz[e]);
    }
    float s = 0.0f;
#pragma unroll
    for (int e = 0; e < 8; e++) {
      p[e] = expf(lz[e] - mx);
      s += p[e];
    }
    const float invs = 1.0f / s;
#pragma unroll
    for (int e = 0; e < 8; e++) p[e] *= invs;
    int i1 = 0;
    for (int e = 1; e < 8; e++)
      if (p[e] > p[i1]) i1 = e;  // strict > keeps lowest index (lax.top_k)
    int i2 = (i1 == 0) ? 1 : 0;
    for (int e = 0; e < 8; e++)
      if (e != i1 && p[e] > p[i2]) i2 = e;
    const float wsum = p[i1] + p[i2];
    eidx[2 * t] = i1;
    eidx[2 * t + 1] = i2;
    ewt[2 * t] = p[i1] / wsum;
    ewt[2 * t + 1] = p[i2] / wsum;
    float* prow = probs_out + (long)t * 8;
    for (int e = 0; e < 8; e++) prow[e] = p[e];
  }
}

// counts[e] += #assignments; 16 blocks x 256 tokens; LDS hist, 8 atomics/block
__global__ __launch_bounds__(256) void bucket_count(const int* __restrict__ eidx,
                                                    int* __restrict__ counts) {
  __shared__ int lcnt[8];
  const int tid = threadIdx.x;
  if (tid < 8) lcnt[tid] = 0;
  __syncthreads();
  const int t = blockIdx.x * 256 + tid;
  atomicAdd(&lcnt[eidx[2 * t]], 1);
  atomicAdd(&lcnt[eidx[2 * t + 1]], 1);
  __syncthreads();
  if (tid < 8) atomicAdd(&counts[tid], lcnt[tid]);
}

// single-thread: padded offsets, tile descriptors, n_tiles
__global__ void setup_tiles(const int* __restrict__ counts, int* __restrict__ poffset,
                            int2* __restrict__ tdesc, int* __restrict__ n_tiles) {
  if (threadIdx.x == 0 && blockIdx.x == 0) {
    int cur = 0, nt = 0;
    for (int e = 0; e < NEXP; e++) {
      poffset[e] = cur;
      const int ntile = (counts[e] + 127) >> 7;
      for (int i = 0; i < ntile; i++) {
        int2 d;
        d.x = e;
        d.y = cur + i * 128;
        tdesc[nt++] = d;
      }
      cur += ntile * 128;
    }
    n_tiles[0] = nt;
  }
}

// scatter: assign padded positions; ridx[p]=token, pos[2t+k]=p.
__global__ __launch_bounds__(256) void bucket_scatter(
    const int* __restrict__ eidx, const int* __restrict__ poffset,
    int* __restrict__ cursors, int* __restrict__ ridx, int* __restrict__ pos) {
  __shared__ int lcnt[8], base[8];
  const int tid = threadIdx.x;
  if (tid < 8) lcnt[tid] = 0;
  __syncthreads();
  const int t = blockIdx.x * 256 + tid;
  const int e0 = eidx[2 * t], e1 = eidx[2 * t + 1];
  const int r0 = atomicAdd(&lcnt[e0], 1);
  const int r1 = atomicAdd(&lcnt[e1], 1);
  __syncthreads();
  if (tid < 8) base[tid] = atomicAdd(&cursors[tid], lcnt[tid]);
  __syncthreads();
  const int p0 = poffset[e0] + base[e0] + r0;
  const int p1 = poffset[e1] + base[e1] + r1;
  ridx[p0] = t;
  ridx[p1] = t;
  pos[2 * t] = p0;
  pos[2 * t + 1] = p1;
}

// single-block aux loss: frac_tokens from counts, frac_probs from probs
__global__ __launch_bounds__(256) void lb_reduce(const float* __restrict__ probs,
                                                 const int* __restrict__ counts,
                                                 float* __restrict__ out) {
  const int tid = threadIdx.x;
  float psum[8] = {};
  for (int tt = 0; tt < 16; tt++) {
    const long t = (long)tid * 16 + tt;
    const float4* pp = (const float4*)(probs + t * 8);
    const float4 p0 = pp[0], p1 = pp[1];
    psum[0] += p0.x; psum[1] += p0.y; psum[2] += p0.z; psum[3] += p0.w;
    psum[4] += p1.x; psum[5] += p1.y; psum[6] += p1.z; psum[7] += p1.w;
  }
#pragma unroll
  for (int e = 0; e < 8; e++)
#pragma unroll
    for (int off = 32; off > 0; off >>= 1) psum[e] += __shfl_down(psum[e], off);
  __shared__ float sp[4][8];
  if ((tid & 63) == 0)
#pragma unroll
    for (int e = 0; e < 8; e++) sp[tid >> 6][e] = psum[e];
  __syncthreads();
  if (tid == 0) {
    float loss = 0.0f;
#pragma unroll
    for (int e = 0; e < 8; e++) {
      const float fp = (sp[0][e] + sp[1][e] + sp[2][e] + sp[3][e]) / 4096.0f;
      const float ft = (float)counts[e] / (4096.0f * 2.0f);
      loss += ft * fp;
    }
    out[0] = 8.0f * loss;
  }
}

// out = rms_norm(x, scale)   (shared path)
__global__ __launch_bounds__(256) void rms_norm_out(const float* __restrict__ x,
                                                    const float* __restrict__ scale,
                                                    float* __restrict__ out) {
  const int t = blockIdx.x;
  const int tid = threadIdx.x;
  const long base = (long)t * DIM + tid * 4;
  const float4 v = *(const float4*)(x + base);
  float ss = v.x * v.x + v.y * v.y + v.z * v.z + v.w * v.w;
#pragma unroll
  for (int off = 32; off > 0; off >>= 1) ss += __shfl_down(ss, off);
  __shared__ float red[4];
  if ((tid & 63) == 0) red[tid >> 6] = ss;
  __syncthreads();
  const float rs = rsqrtf((red[0] + red[1] + red[2] + red[3]) * (1.0f / DIM) + 1e-6f);
  const float4 sc = *(const float4*)(scale + tid * 4);
  float4 o;
  o.x = v.x * rs * sc.x;
  o.y = v.y * rs * sc.y;
  o.z = v.z * rs * sc.z;
  o.w = v.w * rs * sc.w;
  *(float4*)(out + base) = o;
}

// routed combine: v = w0*Hout[p0] + w1*Hout[p1]; out += rms_norm(v, scale)
__global__ __launch_bounds__(256) void combine_norm(
    const float* __restrict__ Hout, const int* __restrict__ pos,
    const float* __restrict__ ewt, const float* __restrict__ scale,
    float* __restrict__ out) {
  const int t = blockIdx.x;
  const int tid = threadIdx.x;
  const float w0 = ewt[2 * t], w1 = ewt[2 * t + 1];
  const long p0 = pos[2 * t], p1 = pos[2 * t + 1];
  const int d = tid * 4;
  const float4 a = *(const float4*)(Hout + p0 * DIM + d);
  const float4 b = *(const float4*)(Hout + p1 * DIM + d);
  float4 v;
  v.x = w0 * a.x + w1 * b.x;
  v.y = w0 * a.y + w1 * b.y;
  v.z = w0 * a.z + w1 * b.z;
  v.w = w0 * a.w + w1 * b.w;
  float ss = v.x * v.x + v.y * v.y + v.z * v.z + v.w * v.w;
#pragma unroll
  for (int off = 32; off > 0; off >>= 1) ss += __shfl_down(ss, off);
  __shared__ float red[4];
  if ((tid & 63) == 0) red[tid >> 6] = ss;
  __syncthreads();
  const float rs = rsqrtf((red[0] + red[1] + red[2] + red[3]) * (1.0f / DIM) + 1e-6f);
  const float4 sc = *(const float4*)(scale + d);
  const long base = (long)t * DIM + d;
  float4 o = *(float4*)(out + base);
  o.x += v.x * rs * sc.x;
  o.y += v.y * rs * sc.y;
  o.z += v.z * rs * sc.z;
  o.w += v.w * rs * sc.w;
  *(float4*)(out + base) = o;
}

// ---------------------------------------------------------------------------
extern "C" void kernel_launch(void* const* d_in, const int* in_sizes, int n_in,
                              void* d_out, int out_size, void* d_ws, size_t ws_size,
                              hipStream_t stream) {
  (void)in_sizes; (void)n_in; (void)out_size; (void)ws_size;
  const float* inputs   = (const float*)d_in[0];
  const float* orig     = (const float*)d_in[1];
  const float* pfs      = (const float*)d_in[2];
  const float* ln2s     = (const float*)d_in[3];
  const float* post1    = (const float*)d_in[4];
  const float* post2    = (const float*)d_in[5];
  const float* router_w = (const float*)d_in[6];
  const float* e_wi0    = (const float*)d_in[7];
  const float* e_wi1    = (const float*)d_in[8];
  const float* e_wo     = (const float*)d_in[9];
  const float* s_wi0    = (const float*)d_in[10];
  const float* s_wi1    = (const float*)d_in[11];
  const float* s_wo     = (const float*)d_in[12];

  char* ws = (char*)d_ws;
  size_t o = 0;
  auto alloc = [&](size_t bytes) -> void* {
    void* p = ws + o;
    o += (bytes + 255) & ~(size_t)255;
    return p;
  };
  u16* s_wi_t  = (u16*)alloc((size_t)2 * FDIM * DIM * 2);        // [2][F,D]
  u16* s_wo_t  = (u16*)alloc((size_t)DIM * FDIM * 2);            // [D,F]
  u16* e_wi_t  = (u16*)alloc((size_t)2 * NEXP * MDIM * DIM * 2); // [2][E,M,D]
  u16* e_wo_t  = (u16*)alloc((size_t)NEXP * DIM * MDIM * 2);     // [E,D,M]
  u16* x_sh    = (u16*)alloc((size_t)T_TOK * DIM * 2);
  u16* routed  = (u16*)alloc((size_t)T_TOK * DIM * 2);
  float* probs = (float*)alloc((size_t)T_TOK * 8 * 4);
  int* eidx    = (int*)alloc((size_t)T_TOK * 2 * 4);
  float* ewt   = (float*)alloc((size_t)T_TOK * 2 * 4);
  int* pos     = (int*)alloc((size_t)T_TOK * 2 * 4);
  int* imeta   = (int*)alloc(256);           // [0..7] counts, [8..15] cursors
  int* poffset = (int*)alloc(64);
  int* n_tiles = (int*)alloc(64);
  int2* tdesc  = (int2*)alloc(MAXTILES * 8);
  int* ridx    = (int*)alloc((size_t)HROWS * 4);
  float* racc  = (float*)alloc((size_t)T_TOK * DIM * 4);
  u16* Hs      = (u16*)alloc((size_t)2 * T_TOK * FDIM * 2);      // [2][T,F]
  u16* H       = (u16*)alloc((size_t)2 * HROWS * MDIM * 2);      // [2][HROWS,M]
  float* Hout  = (float*)alloc((size_t)HROWS * DIM * 4);

  int* counts = imeta;
  int* cursors = imeta + 8;

  hipMemsetAsync(imeta, 0, 64, stream);
  hipMemsetAsync(ridx, 0, (size_t)HROWS * 4, stream);

  // ---- weight transposes (f32 -> f16 B^T layouts) ----
  transpose_cvt<<<dim3(FDIM / 32, DIM / 32, 1), 256, 0, stream>>>(s_wi0, s_wi_t, DIM, FDIM);
  transpose_cvt<<<dim3(FDIM / 32, DIM / 32, 1), 256, 0, stream>>>(s_wi1, s_wi_t + (size_t)FDIM * DIM, DIM, FDIM);
  transpose_cvt<<<dim3(DIM / 32, FDIM / 32, 1), 256, 0, stream>>>(s_wo, s_wo_t, FDIM, DIM);
  transpose_cvt<<<dim3(MDIM / 32, DIM / 32, NEXP), 256, 0, stream>>>(e_wi0, e_wi_t, DIM, MDIM);
  transpose_cvt<<<dim3(MDIM / 32, DIM / 32, NEXP), 256, 0, stream>>>(e_wi1, e_wi_t + (size_t)NEXP * MDIM * DIM, DIM, MDIM);
  transpose_cvt<<<dim3(DIM / 32, MDIM / 32, NEXP), 256, 0, stream>>>(e_wo, e_wo_t, MDIM, DIM);

  cvt_f16<<<T_TOK * DIM / 4 / 256, 256, 0, stream>>>(inputs, x_sh, T_TOK * DIM);
  router_kernel<<<T_TOK, 256, 0, stream>>>(orig, pfs, ln2s, router_w, routed, eidx, ewt, probs);

  // ---- bucketing ----
  bucket_count<<<16, 256, 0, stream>>>(eidx, counts);
  setup_tiles<<<1, 64, 0, stream>>>(counts, poffset, tdesc, n_tiles);
  bucket_scatter<<<16, 256, 0, stream>>>(eidx, poffset, cursors, ridx, pos);
  lb_reduce<<<1, 256, 0, stream>>>(probs, counts, (float*)d_out + (size_t)T_TOK * DIM);

  // ---- shared expert path ----
  gemm_bt<1><<<dim3(FDIM / 128, T_TOK / 128, 2), 256, 0, stream>>>(
      x_sh, s_wi_t, Hs, FDIM, DIM, (long)FDIM * DIM, (long)T_TOK * FDIM);
  gelu_mul<<<(int)((long)T_TOK * FDIM / 8 / 256), 256, 0, stream>>>(
      Hs, Hs + (size_t)T_TOK * FDIM, (long)T_TOK * FDIM);
  gemm_bt<0><<<dim3(DIM / 128, T_TOK / 128, 1), 256, 0, stream>>>(
      Hs, s_wo_t, racc, DIM, FDIM, 0, 0);
  rms_norm_out<<<T_TOK, 256, 0, stream>>>(racc, post1, (float*)d_out);

  // ---- routed experts: sparse grouped GEMMs ----
  gemm_moe<1, 1><<<dim3(MDIM / 128, MAXTILES, 2), 256, 0, stream>>>(
      routed, e_wi_t, H, ridx, tdesc, n_tiles, MDIM, DIM,
      (long)MDIM * DIM, (long)NEXP * MDIM * DIM, (long)HROWS * MDIM);
  gelu_mul<<<(int)((long)HROWS * MDIM / 8 / 256), 256, 0, stream>>>(
      H, H + (size_t)HROWS * MDIM, (long)HROWS * MDIM);
  gemm_moe<0, 0><<<dim3(DIM / 128, MAXTILES, 1), 256, 0, stream>>>(
      H, e_wo_t, Hout, ridx, tdesc, n_tiles, DIM, MDIM,
      (long)DIM * MDIM, 0, 0);
  combine_norm<<<T_TOK, 256, 0, stream>>>(Hout, pos, ewt, post2, (float*)d_out);
}

// Round 4
// 453.019 us; speedup vs baseline: 3.1172x; 1.1188x over previous
//
#include <hip/hip_runtime.h>
#include <stdint.h>

// ---------------------------------------------------------------------------
// Gemma4 MoE block on gfx950. FP16 MFMA (16x16x32) GEMMs, f32 accumulation.
// R1: atomic-free router + lb_reduce.
// R2: sparse top-2 routed experts (tile-padded bucketing + grouped GEMMs).
// R3: gemm_gated (dual-B, 8-wave, gelu*mul fused in epilogue via LDS acc
//     exchange) for both in-GEMMs; split-K=2 out-GEMMs (2x blocks) with
//     partial sums folded into rms/combine epilogues; fewer launches (13).
// ---------------------------------------------------------------------------

typedef unsigned short u16;
typedef u16 u16x4 __attribute__((ext_vector_type(4)));
typedef u16 u16x8 __attribute__((ext_vector_type(8)));
typedef _Float16 f16x8 __attribute__((ext_vector_type(8)));
typedef float f32x4 __attribute__((ext_vector_type(4)));
typedef __attribute__((address_space(1))) void* as1_vp;
typedef __attribute__((address_space(3))) void* as3_vp;

#define T_TOK 4096
#define DIM   1024
#define FDIM  2048
#define MDIM  1024
#define NEXP  8
#define MAXTILES 72            // sum ceil(cnt_e/128) <= 64 + 7, padded
#define HROWS (MAXTILES * 128) // 9216 padded assignment rows

__device__ __forceinline__ u16 f2h(float f) {
  _Float16 h = (_Float16)f;
  return __builtin_bit_cast(u16, h);
}
__device__ __forceinline__ float h2f(u16 u) {
  return (float)__builtin_bit_cast(_Float16, u);
}
// tanh-approx gelu rewritten exactly as x*sigmoid(2y): cheap __expf + div
__device__ __forceinline__ float gelu_f(float x) {
  const float y2 = x * (1.5957691216f + 0.0713548163f * x * x);
  return x / (1.0f + __expf(-y2));
}
__device__ __forceinline__ void async_copy16(const void* g, void* l) {
  __builtin_amdgcn_global_load_lds((as1_vp)(uintptr_t)g,
                                   (as3_vp)(uint32_t)(uintptr_t)l, 16, 0, 0);
}
__device__ __forceinline__ f16x8 lds_frag(const u16* p) {
  return __builtin_bit_cast(f16x8, *(const u16x8*)p);
}

// ---------------------------------------------------------------------------
// Gated dual-GEMM: H[M,N](f16) = gelu(A@B0) * (A@B1), A[M,K] f16 row-major,
// B0t/B1t = [N,K]. 512 threads = 8 waves: waves 0-3 acc A@B0 (2x2 of 64x64),
// waves 4-7 acc A@B1 for the SAME tile coords. Epilogue: waves 4-7 push f16
// acc through LDS (lane-linear, conflict-free), waves 0-3 combine + store.
// GATHER=1: A rows indirected via ridx; C rows are padded positions.
// ---------------------------------------------------------------------------
template <int GATHER>
__global__ __launch_bounds__(512) void gemm_gated(
    const u16* __restrict__ A, const u16* __restrict__ B0t,
    const u16* __restrict__ B1t, u16* __restrict__ H,
    const int* __restrict__ ridx, const int2* __restrict__ tdesc,
    const int* __restrict__ n_tiles, int N, int K, long strideBe) {
  if (GATHER && (int)blockIdx.y >= *n_tiles) return;
  __shared__ __align__(16) u16 lds[16384];  // 32 KB: staging 24 KB / exchange 32 KB
  u16* As = lds;
  u16* Bs0 = lds + 4096;
  u16* Bs1 = lds + 8192;
  const int tid = threadIdx.x;
  const int lane = tid & 63;
  const int wave = tid >> 6;      // 0..7
  const int wv = wave & 3;
  const bool grp1 = wave >= 4;    // B1 group
  long prow0;
  if (GATHER) {
    const int2 td = tdesc[blockIdx.y];
    prow0 = td.y;
    B0t += (long)td.x * strideBe;
    B1t += (long)td.x * strideBe;
  } else {
    prow0 = (long)blockIdx.y * 128;
  }
  const long bn = (long)blockIdx.x * 128;
  const int wm = (wv >> 1) * 64;
  const int wn = (wv & 1) * 64;

  f32x4 acc[4][4] = {};
  // staging: 512 chunks (16B) per tile; thread stages 1 chunk of each tile
  long arow;
  if (GATHER) arow = ridx[prow0 + (tid >> 2)];
  else        arow = prow0 + (tid >> 2);
  const u16* Ag  = A + arow * (long)K + (tid & 3) * 8;
  const u16* B0g = B0t + (bn + (tid >> 2)) * (long)K + (tid & 3) * 8;
  const u16* B1g = B1t + (bn + (tid >> 2)) * (long)K + (tid & 3) * 8;
  u16* Asl  = &As[tid * 8];
  u16* Bs0l = &Bs0[tid * 8];
  u16* Bs1l = &Bs1[tid * 8];
  const int fr = lane & 15;
  const int fk = (lane >> 4) * 8;
  const u16* Bs = grp1 ? Bs1 : Bs0;

  for (int k0 = 0; k0 < K; k0 += 32) {
    async_copy16(Ag + k0, Asl);
    async_copy16(B0g + k0, Bs0l);
    async_copy16(B1g + k0, Bs1l);
    __syncthreads();
    f16x8 af[4], bq[4];
#pragma unroll
    for (int i = 0; i < 4; i++) af[i] = lds_frag(&As[(wm + i * 16 + fr) * 32 + fk]);
#pragma unroll
    for (int i = 0; i < 4; i++) bq[i] = lds_frag(&Bs[(wn + i * 16 + fr) * 32 + fk]);
#pragma unroll
    for (int mi = 0; mi < 4; mi++)
#pragma unroll
      for (int ni = 0; ni < 4; ni++)
        acc[mi][ni] = __builtin_amdgcn_mfma_f32_16x16x32_f16(af[mi], bq[ni], acc[mi][ni], 0, 0, 0);
    __syncthreads();
  }

  // acc1 exchange: region per wv = 4096 u16; chunk c: addr = wv*4096+c*512+lane*8
  if (grp1) {
    u16 tmp[64];
#pragma unroll
    for (int mi = 0; mi < 4; mi++)
#pragma unroll
      for (int ni = 0; ni < 4; ni++)
#pragma unroll
        for (int r = 0; r < 4; r++) tmp[(mi * 4 + ni) * 4 + r] = f2h(acc[mi][ni][r]);
#pragma unroll
    for (int c = 0; c < 8; c++)
      *(u16x8*)&lds[wv * 4096 + c * 512 + lane * 8] = *(u16x8*)&tmp[c * 8];
  }
  __syncthreads();
  if (!grp1) {
    u16 tmp[64];
#pragma unroll
    for (int c = 0; c < 8; c++)
      *(u16x8*)&tmp[c * 8] = *(const u16x8*)&lds[wv * 4096 + c * 512 + lane * 8];
    const int er = (lane >> 4) * 4;  // C/D: col=lane&15, row=(lane>>4)*4+reg
    const int ec = lane & 15;
#pragma unroll
    for (int mi = 0; mi < 4; mi++)
#pragma unroll
      for (int r = 0; r < 4; r++) {
        const long row = prow0 + wm + mi * 16 + er + r;
#pragma unroll
        for (int ni = 0; ni < 4; ni++)
          H[row * N + bn + wn + ni * 16 + ec] =
              f2h(gelu_f(acc[mi][ni][r]) * h2f(tmp[(mi * 4 + ni) * 4 + r]));
      }
  }
}

// ---------------------------------------------------------------------------
// Out-GEMM with split-K (grid.z selects K-half): C[.,N] f32 partials.
// MOE=1: rows from tile descriptors (padded positions), expert B via tdesc.x.
// ---------------------------------------------------------------------------
template <int MOE>
__global__ __launch_bounds__(256) void gemm_out(
    const u16* __restrict__ A, const u16* __restrict__ Bt, float* __restrict__ C,
    const int2* __restrict__ tdesc, const int* __restrict__ n_tiles,
    int N, int Kfull, int Khalf, long strideBe, long strideCz) {
  if (MOE && (int)blockIdx.y >= *n_tiles) return;
  __shared__ __align__(16) u16 As[128 * 32];
  __shared__ __align__(16) u16 Bs[128 * 32];
  const int tid = threadIdx.x;
  const int lane = tid & 63;
  const int wave = tid >> 6;
  const int wm = (wave >> 1) * 64;
  const int wn = (wave & 1) * 64;
  long bm;
  if (MOE) {
    const int2 td = tdesc[blockIdx.y];
    bm = td.y;
    Bt += (long)td.x * strideBe;
  } else {
    bm = (long)blockIdx.y * 128;
  }
  const long bn = (long)blockIdx.x * 128;
  const int kbase = blockIdx.z * Khalf;
  C += (long)blockIdx.z * strideCz;

  f32x4 acc[4][4] = {};
  const int c0 = tid, c1 = tid + 256;
  const u16* Ag0 = A + (bm + (c0 >> 2)) * (long)Kfull + kbase + (c0 & 3) * 8;
  const u16* Ag1 = A + (bm + (c1 >> 2)) * (long)Kfull + kbase + (c1 & 3) * 8;
  const u16* Bg0 = Bt + (bn + (c0 >> 2)) * (long)Kfull + kbase + (c0 & 3) * 8;
  const u16* Bg1 = Bt + (bn + (c1 >> 2)) * (long)Kfull + kbase + (c1 & 3) * 8;
  u16 *As0 = &As[c0 * 8], *As1 = &As[c1 * 8];
  u16 *Bs0 = &Bs[c0 * 8], *Bs1 = &Bs[c1 * 8];
  const int fr = lane & 15;
  const int fk = (lane >> 4) * 8;

  for (int k0 = 0; k0 < Khalf; k0 += 32) {
    async_copy16(Ag0 + k0, As0);
    async_copy16(Ag1 + k0, As1);
    async_copy16(Bg0 + k0, Bs0);
    async_copy16(Bg1 + k0, Bs1);
    __syncthreads();
    f16x8 af[4], bq[4];
#pragma unroll
    for (int i = 0; i < 4; i++) af[i] = lds_frag(&As[(wm + i * 16 + fr) * 32 + fk]);
#pragma unroll
    for (int i = 0; i < 4; i++) bq[i] = lds_frag(&Bs[(wn + i * 16 + fr) * 32 + fk]);
#pragma unroll
    for (int mi = 0; mi < 4; mi++)
#pragma unroll
      for (int ni = 0; ni < 4; ni++)
        acc[mi][ni] = __builtin_amdgcn_mfma_f32_16x16x32_f16(af[mi], bq[ni], acc[mi][ni], 0, 0, 0);
    __syncthreads();
  }

  const int er = (lane >> 4) * 4;
  const int ec = lane & 15;
#pragma unroll
  for (int mi = 0; mi < 4; mi++)
#pragma unroll
    for (int r = 0; r < 4; r++) {
      const long row = bm + wm + mi * 16 + er + r;
#pragma unroll
      for (int ni = 0; ni < 4; ni++)
        C[row * N + bn + wn + ni * 16 + ec] = acc[mi][ni][r];
    }
}

// ---------------------------------------------------------------------------
// Transpose f32 [R,C] -> f16 [C,R]; dual-source variant batches over z.
// ---------------------------------------------------------------------------
__global__ __launch_bounds__(256) void transpose_cvt2(
    const float* __restrict__ s0, const float* __restrict__ s1,
    u16* __restrict__ dst, int R, int C, int zsplit) {
  __shared__ float tile[32][33];
  const int z = blockIdx.z;
  const float* src = (z < zsplit) ? s0 + (long)z * R * C
                                  : s1 + (long)(z - zsplit) * R * C;
  u16* d = dst + (long)z * R * C;
  const int c0 = blockIdx.x * 32, r0 = blockIdx.y * 32;
  const int tx = threadIdx.x & 31, ty = threadIdx.x >> 5;
#pragma unroll
  for (int i = 0; i < 32; i += 8) tile[ty + i][tx] = src[(long)(r0 + ty + i) * C + c0 + tx];
  __syncthreads();
#pragma unroll
  for (int i = 0; i < 32; i += 8) d[(long)(c0 + ty + i) * R + r0 + tx] = f2h(tile[tx][ty + i]);
}

__global__ __launch_bounds__(256) void cvt_f16(const float* __restrict__ s,
                                               u16* __restrict__ d, int n) {
  const int i = (blockIdx.x * 256 + threadIdx.x) * 4;
  if (i < n) {
    const float4 v = *(const float4*)(s + i);
    u16x4 o = {f2h(v.x), f2h(v.y), f2h(v.z), f2h(v.w)};
    *(u16x4*)(d + i) = o;
  }
}

// ---------------------------------------------------------------------------
// Router: routed_in = rms_norm(orig,ln2s) f16; softmax/top2; eidx/ewt/probs.
// ---------------------------------------------------------------------------
__global__ __launch_bounds__(256) void router_kernel(
    const float* __restrict__ orig, const float* __restrict__ pfs,
    const float* __restrict__ ln2s, const float* __restrict__ rw,
    u16* __restrict__ routed_in, int* __restrict__ eidx, float* __restrict__ ewt,
    float* __restrict__ probs_out) {
  const int t = blockIdx.x;
  const int tid = threadIdx.x;
  const float* x = orig + (long)t * DIM;
  const int d = tid * 4;
  const float4 v = *(const float4*)(x + d);
  float ss = v.x * v.x + v.y * v.y + v.z * v.z + v.w * v.w;
#pragma unroll
  for (int off = 32; off > 0; off >>= 1) ss += __shfl_down(ss, off);
  __shared__ float red[4];
  __shared__ float lred[4][8];
  if ((tid & 63) == 0) red[tid >> 6] = ss;
  __syncthreads();
  const float rs = rsqrtf((red[0] + red[1] + red[2] + red[3]) * (1.0f / DIM) + 1e-6f);

  const float4 l2 = *(const float4*)(ln2s + d);
  u16x4 ro = {f2h(v.x * rs * l2.x), f2h(v.y * rs * l2.y), f2h(v.z * rs * l2.z),
              f2h(v.w * rs * l2.w)};
  *(u16x4*)(routed_in + (long)t * DIM + d) = ro;

  const float4 pf = *(const float4*)(pfs + d);
  const float c = rs * 0.03125f;  // D^-0.5
  const float g0 = v.x * c * pf.x, g1 = v.y * c * pf.y;
  const float g2 = v.z * c * pf.z, g3 = v.w * c * pf.w;
  float lg[8];
#pragma unroll
  for (int e = 0; e < 8; e++)
    lg[e] = g0 * rw[(d + 0) * 8 + e] + g1 * rw[(d + 1) * 8 + e] +
            g2 * rw[(d + 2) * 8 + e] + g3 * rw[(d + 3) * 8 + e];
#pragma unroll
  for (int e = 0; e < 8; e++)
#pragma unroll
    for (int off = 32; off > 0; off >>= 1) lg[e] += __shfl_down(lg[e], off);
  if ((tid & 63) == 0)
#pragma unroll
    for (int e = 0; e < 8; e++) lred[tid >> 6][e] = lg[e];
  __syncthreads();
  if (tid == 0) {
    float lz[8], p[8];
    float mx = -1e30f;
#pragma unroll
    for (int e = 0; e < 8; e++) {
      lz[e] = lred[0][e] + lred[1][e] + lred[2][e] + lred[3][e];
      mx = fmaxf(mx, lz[e]);
    }
    float s = 0.0f;
#pragma unroll
    for (int e = 0; e < 8; e++) {
      p[e] = expf(lz[e] - mx);
      s += p[e];
    }
    const float invs = 1.0f / s;
#pragma unroll
    for (int e = 0; e < 8; e++) p[e] *= invs;
    int i1 = 0;
    for (int e = 1; e < 8; e++)
      if (p[e] > p[i1]) i1 = e;  // strict > keeps lowest index (lax.top_k)
    int i2 = (i1 == 0) ? 1 : 0;
    for (int e = 0; e < 8; e++)
      if (e != i1 && p[e] > p[i2]) i2 = e;
    const float wsum = p[i1] + p[i2];
    eidx[2 * t] = i1;
    eidx[2 * t + 1] = i2;
    ewt[2 * t] = p[i1] / wsum;
    ewt[2 * t + 1] = p[i2] / wsum;
    float* prow = probs_out + (long)t * 8;
    for (int e = 0; e < 8; e++) prow[e] = p[e];
  }
}

// counts[e] += #assignments; LDS hist, 8 global atomics/block
__global__ __launch_bounds__(256) void bucket_count(const int* __restrict__ eidx,
                                                    int* __restrict__ counts) {
  __shared__ int lcnt[8];
  const int tid = threadIdx.x;
  if (tid < 8) lcnt[tid] = 0;
  __syncthreads();
  const int t = blockIdx.x * 256 + tid;
  atomicAdd(&lcnt[eidx[2 * t]], 1);
  atomicAdd(&lcnt[eidx[2 * t + 1]], 1);
  __syncthreads();
  if (tid < 8) atomicAdd(&counts[tid], lcnt[tid]);
}

__global__ void setup_tiles(const int* __restrict__ counts, int* __restrict__ poffset,
                            int2* __restrict__ tdesc, int* __restrict__ n_tiles) {
  if (threadIdx.x == 0 && blockIdx.x == 0) {
    int cur = 0, nt = 0;
    for (int e = 0; e < NEXP; e++) {
      poffset[e] = cur;
      const int ntile = (counts[e] + 127) >> 7;
      for (int i = 0; i < ntile; i++) {
        int2 d;
        d.x = e;
        d.y = cur + i * 128;
        tdesc[nt++] = d;
      }
      cur += ntile * 128;
    }
    n_tiles[0] = nt;
  }
}

__global__ __launch_bounds__(256) void bucket_scatter(
    const int* __restrict__ eidx, const int* __restrict__ poffset,
    int* __restrict__ cursors, int* __restrict__ ridx, int* __restrict__ pos) {
  __shared__ int lcnt[8], base[8];
  const int tid = threadIdx.x;
  if (tid < 8) lcnt[tid] = 0;
  __syncthreads();
  const int t = blockIdx.x * 256 + tid;
  const int e0 = eidx[2 * t], e1 = eidx[2 * t + 1];
  const int r0 = atomicAdd(&lcnt[e0], 1);
  const int r1 = atomicAdd(&lcnt[e1], 1);
  __syncthreads();
  if (tid < 8) base[tid] = atomicAdd(&cursors[tid], lcnt[tid]);
  __syncthreads();
  const int p0 = poffset[e0] + base[e0] + r0;
  const int p1 = poffset[e1] + base[e1] + r1;
  ridx[p0] = t;
  ridx[p1] = t;
  pos[2 * t] = p0;
  pos[2 * t + 1] = p1;
}

__global__ __launch_bounds__(256) void lb_reduce(const float* __restrict__ probs,
                                                 const int* __restrict__ counts,
                                                 float* __restrict__ out) {
  const int tid = threadIdx.x;
  float psum[8] = {};
  for (int tt = 0; tt < 16; tt++) {
    const long t = (long)tid * 16 + tt;
    const float4* pp = (const float4*)(probs + t * 8);
    const float4 p0 = pp[0], p1 = pp[1];
    psum[0] += p0.x; psum[1] += p0.y; psum[2] += p0.z; psum[3] += p0.w;
    psum[4] += p1.x; psum[5] += p1.y; psum[6] += p1.z; psum[7] += p1.w;
  }
#pragma unroll
  for (int e = 0; e < 8; e++)
#pragma unroll
    for (int off = 32; off > 0; off >>= 1) psum[e] += __shfl_down(psum[e], off);
  __shared__ float sp[4][8];
  if ((tid & 63) == 0)
#pragma unroll
    for (int e = 0; e < 8; e++) sp[tid >> 6][e] = psum[e];
  __syncthreads();
  if (tid == 0) {
    float loss = 0.0f;
#pragma unroll
    for (int e = 0; e < 8; e++) {
      const float fp = (sp[0][e] + sp[1][e] + sp[2][e] + sp[3][e]) / 4096.0f;
      const float ft = (float)counts[e] / (4096.0f * 2.0f);
      loss += ft * fp;
    }
    out[0] = 8.0f * loss;
  }
}

// out = rms_norm(x0+x1, scale)  (shared path; sums split-K partials)
__global__ __launch_bounds__(256) void rms_norm_out(const float* __restrict__ x,
                                                    const float* __restrict__ scale,
                                                    float* __restrict__ out) {
  const int t = blockIdx.x;
  const int tid = threadIdx.x;
  const long base = (long)t * DIM + tid * 4;
  const float4 a = *(const float4*)(x + base);
  const float4 b = *(const float4*)(x + base + (long)T_TOK * DIM);
  float4 v;
  v.x = a.x + b.x; v.y = a.y + b.y; v.z = a.z + b.z; v.w = a.w + b.w;
  float ss = v.x * v.x + v.y * v.y + v.z * v.z + v.w * v.w;
#pragma unroll
  for (int off = 32; off > 0; off >>= 1) ss += __shfl_down(ss, off);
  __shared__ float red[4];
  if ((tid & 63) == 0) red[tid >> 6] = ss;
  __syncthreads();
  const float rs = rsqrtf((red[0] + red[1] + red[2] + red[3]) * (1.0f / DIM) + 1e-6f);
  const float4 sc = *(const float4*)(scale + tid * 4);
  float4 o;
  o.x = v.x * rs * sc.x;
  o.y = v.y * rs * sc.y;
  o.z = v.z * rs * sc.z;
  o.w = v.w * rs * sc.w;
  *(float4*)(out + base) = o;
}

// routed combine (sums split-K partials): v = w0*(H0+H1)[p0] + w1*(H0+H1)[p1]
__global__ __launch_bounds__(256) void combine_norm(
    const float* __restrict__ Hout, const int* __restrict__ pos,
    const float* __restrict__ ewt, const float* __restrict__ scale,
    float* __restrict__ out) {
  const int t = blockIdx.x;
  const int tid = threadIdx.x;
  const float w0 = ewt[2 * t], w1 = ewt[2 * t + 1];
  const long p0 = pos[2 * t], p1 = pos[2 * t + 1];
  const int d = tid * 4;
  const long SK = (long)HROWS * DIM;
  const float4 a0 = *(const float4*)(Hout + p0 * DIM + d);
  const float4 a1 = *(const float4*)(Hout + SK + p0 * DIM + d);
  const float4 b0 = *(const float4*)(Hout + p1 * DIM + d);
  const float4 b1 = *(const float4*)(Hout + SK + p1 * DIM + d);
  float4 v;
  v.x = w0 * (a0.x + a1.x) + w1 * (b0.x + b1.x);
  v.y = w0 * (a0.y + a1.y) + w1 * (b0.y + b1.y);
  v.z = w0 * (a0.z + a1.z) + w1 * (b0.z + b1.z);
  v.w = w0 * (a0.w + a1.w) + w1 * (b0.w + b1.w);
  float ss = v.x * v.x + v.y * v.y + v.z * v.z + v.w * v.w;
#pragma unroll
  for (int off = 32; off > 0; off >>= 1) ss += __shfl_down(ss, off);
  __shared__ float red[4];
  if ((tid & 63) == 0) red[tid >> 6] = ss;
  __syncthreads();
  const float rs = rsqrtf((red[0] + red[1] + red[2] + red[3]) * (1.0f / DIM) + 1e-6f);
  const float4 sc = *(const float4*)(scale + d);
  const long base = (long)t * DIM + d;
  float4 o = *(float4*)(out + base);
  o.x += v.x * rs * sc.x;
  o.y += v.y * rs * sc.y;
  o.z += v.z * rs * sc.z;
  o.w += v.w * rs * sc.w;
  *(float4*)(out + base) = o;
}

// ---------------------------------------------------------------------------
extern "C" void kernel_launch(void* const* d_in, const int* in_sizes, int n_in,
                              void* d_out, int out_size, void* d_ws, size_t ws_size,
                              hipStream_t stream) {
  (void)in_sizes; (void)n_in; (void)out_size; (void)ws_size;
  const float* inputs   = (const float*)d_in[0];
  const float* orig     = (const float*)d_in[1];
  const float* pfs      = (const float*)d_in[2];
  const float* ln2s     = (const float*)d_in[3];
  const float* post1    = (const float*)d_in[4];
  const float* post2    = (const float*)d_in[5];
  const float* router_w = (const float*)d_in[6];
  const float* e_wi0    = (const float*)d_in[7];
  const float* e_wi1    = (const float*)d_in[8];
  const float* e_wo     = (const float*)d_in[9];
  const float* s_wi0    = (const float*)d_in[10];
  const float* s_wi1    = (const float*)d_in[11];
  const float* s_wo     = (const float*)d_in[12];

  char* ws = (char*)d_ws;
  size_t o = 0;
  auto alloc = [&](size_t bytes) -> void* {
    void* p = ws + o;
    o += (bytes + 255) & ~(size_t)255;
    return p;
  };
  u16* s_wi_t  = (u16*)alloc((size_t)2 * FDIM * DIM * 2);        // [2][F,D]
  u16* s_wo_t  = (u16*)alloc((size_t)DIM * FDIM * 2);            // [D,F]
  u16* e_wi_t  = (u16*)alloc((size_t)2 * NEXP * MDIM * DIM * 2); // [2][E,M,D]
  u16* e_wo_t  = (u16*)alloc((size_t)NEXP * DIM * MDIM * 2);     // [E,D,M]
  u16* x_sh    = (u16*)alloc((size_t)T_TOK * DIM * 2);
  u16* routed  = (u16*)alloc((size_t)T_TOK * DIM * 2);
  float* probs = (float*)alloc((size_t)T_TOK * 8 * 4);
  int* eidx    = (int*)alloc((size_t)T_TOK * 2 * 4);
  float* ewt   = (float*)alloc((size_t)T_TOK * 2 * 4);
  int* pos     = (int*)alloc((size_t)T_TOK * 2 * 4);
  int* imeta   = (int*)alloc(256);           // [0..7] counts, [8..15] cursors
  int* poffset = (int*)alloc(64);
  int* n_tiles = (int*)alloc(64);
  int2* tdesc  = (int2*)alloc(MAXTILES * 8);
  int* ridx    = (int*)alloc((size_t)HROWS * 4);
  float* racc  = (float*)alloc((size_t)2 * T_TOK * DIM * 4);     // split-K partials
  u16* Hs      = (u16*)alloc((size_t)T_TOK * FDIM * 2);          // gated h (shared)
  u16* H       = (u16*)alloc((size_t)HROWS * MDIM * 2);          // gated h (routed)
  float* Hout  = (float*)alloc((size_t)2 * HROWS * DIM * 4);     // split-K partials

  int* counts = imeta;
  int* cursors = imeta + 8;

  hipMemsetAsync(imeta, 0, 64, stream);
  hipMemsetAsync(ridx, 0, (size_t)HROWS * 4, stream);

  // ---- weight transposes (f32 -> f16 B^T layouts), 4 launches ----
  transpose_cvt2<<<dim3(FDIM / 32, DIM / 32, 2), 256, 0, stream>>>(
      s_wi0, s_wi1, s_wi_t, DIM, FDIM, 1);
  transpose_cvt2<<<dim3(DIM / 32, FDIM / 32, 1), 256, 0, stream>>>(
      s_wo, s_wo, s_wo_t, FDIM, DIM, 1);
  transpose_cvt2<<<dim3(MDIM / 32, DIM / 32, 16), 256, 0, stream>>>(
      e_wi0, e_wi1, e_wi_t, DIM, MDIM, 8);
  transpose_cvt2<<<dim3(DIM / 32, MDIM / 32, 8), 256, 0, stream>>>(
      e_wo, e_wo, e_wo_t, MDIM, DIM, 8);

  cvt_f16<<<T_TOK * DIM / 4 / 256, 256, 0, stream>>>(inputs, x_sh, T_TOK * DIM);
  router_kernel<<<T_TOK, 256, 0, stream>>>(orig, pfs, ln2s, router_w, routed, eidx, ewt, probs);

  // ---- bucketing ----
  bucket_count<<<16, 256, 0, stream>>>(eidx, counts);
  setup_tiles<<<1, 64, 0, stream>>>(counts, poffset, tdesc, n_tiles);
  bucket_scatter<<<16, 256, 0, stream>>>(eidx, poffset, cursors, ridx, pos);

  // ---- shared expert path ----
  gemm_gated<0><<<dim3(FDIM / 128, T_TOK / 128, 1), 512, 0, stream>>>(
      x_sh, s_wi_t, s_wi_t + (size_t)FDIM * DIM, Hs, nullptr, nullptr, nullptr,
      FDIM, DIM, 0);
  gemm_out<0><<<dim3(DIM / 128, T_TOK / 128, 2), 256, 0, stream>>>(
      Hs, s_wo_t, racc, nullptr, nullptr, DIM, FDIM, FDIM / 2, 0, (long)T_TOK * DIM);
  rms_norm_out<<<T_TOK, 256, 0, stream>>>(racc, post1, (float*)d_out);

  // ---- routed experts: sparse gated GEMM + split-K out-GEMM ----
  gemm_gated<1><<<dim3(MDIM / 128, MAXTILES, 1), 512, 0, stream>>>(
      routed, e_wi_t, e_wi_t + (size_t)NEXP * MDIM * DIM, H, ridx, tdesc, n_tiles,
      MDIM, DIM, (long)MDIM * DIM);
  gemm_out<1><<<dim3(DIM / 128, MAXTILES, 2), 256, 0, stream>>>(
      H, e_wo_t, Hout, tdesc, n_tiles, DIM, MDIM, MDIM / 2,
      (long)DIM * MDIM, (long)HROWS * DIM);
  combine_norm<<<T_TOK, 256, 0, stream>>>(Hout, pos, ewt, post2, (float*)d_out);

  lb_reduce<<<1, 256, 0, stream>>>(probs, counts, (float*)d_out + (size_t)T_TOK * DIM);
}

// Round 5
// 447.648 us; speedup vs baseline: 3.1546x; 1.0120x over previous
//
#include <hip/hip_runtime.h>
#include <stdint.h>

// ---------------------------------------------------------------------------
// Gemma4 MoE block on gfx950. FP16 MFMA (16x16x32) GEMMs, f32 accumulation.
// R1: atomic-free router + lb_reduce.
// R2: sparse top-2 routed experts (tile-padded bucketing + grouped GEMMs).
// R3: fused gated dual-GEMM; split-K=2 out-GEMMs; 13 launches.
// R4: gemm_gated rebuilt: 256 thr / 4 waves, DUAL acc per wave (in-register
//     gelu*mul, no LDS exchange), BK=64 (4x barrier amortization), XOR chunk
//     swizzle via global-source permutation (bank-conflict-free frag reads).
//     512-thr version was 1 block/CU -> whole-CU barrier stalls (m114).
// ---------------------------------------------------------------------------

typedef unsigned short u16;
typedef u16 u16x4 __attribute__((ext_vector_type(4)));
typedef u16 u16x8 __attribute__((ext_vector_type(8)));
typedef _Float16 f16x8 __attribute__((ext_vector_type(8)));
typedef float f32x4 __attribute__((ext_vector_type(4)));
typedef __attribute__((address_space(1))) void* as1_vp;
typedef __attribute__((address_space(3))) void* as3_vp;

#define T_TOK 4096
#define DIM   1024
#define FDIM  2048
#define MDIM  1024
#define NEXP  8
#define MAXTILES 72            // sum ceil(cnt_e/128) <= 64 + 7, padded
#define HROWS (MAXTILES * 128) // 9216 padded assignment rows

__device__ __forceinline__ u16 f2h(float f) {
  _Float16 h = (_Float16)f;
  return __builtin_bit_cast(u16, h);
}
__device__ __forceinline__ float h2f(u16 u) {
  return (float)__builtin_bit_cast(_Float16, u);
}
// tanh-approx gelu rewritten exactly as x*sigmoid(2y): cheap __expf + div
__device__ __forceinline__ float gelu_f(float x) {
  const float y2 = x * (1.5957691216f + 0.0713548163f * x * x);
  return x / (1.0f + __expf(-y2));
}
__device__ __forceinline__ void async_copy16(const void* g, void* l) {
  __builtin_amdgcn_global_load_lds((as1_vp)(uintptr_t)g,
                                   (as3_vp)(uint32_t)(uintptr_t)l, 16, 0, 0);
}
__device__ __forceinline__ f16x8 lds_frag(const u16* p) {
  return __builtin_bit_cast(f16x8, *(const u16x8*)p);
}

// ---------------------------------------------------------------------------
// Gated dual-GEMM: H[M,N](f16) = gelu(A@B0) * (A@B1). A[M,K] f16 row-major,
// B0t/B1t = [N,K]. 256 threads = 4 waves (2x2 of 64x64); EACH wave holds both
// acc0 (A@B0) and acc1 (A@B1) -> gelu*mul fused in-register, no exchange.
// BK=64: 48 KB LDS, 128 MFMA/wave per barrier pair. Chunk-XOR swizzle is
// applied on the GLOBAL source index (LDS dest of global_load_lds must stay
// lane-linear); fragment reads then spread across all 8 bank groups.
// GATHER=1: A rows indirected via ridx; C rows are padded positions.
// ---------------------------------------------------------------------------
template <int GATHER>
__global__ __launch_bounds__(256, 2) void gemm_gated(
    const u16* __restrict__ A, const u16* __restrict__ B0t,
    const u16* __restrict__ B1t, u16* __restrict__ H,
    const int* __restrict__ ridx, const int2* __restrict__ tdesc,
    const int* __restrict__ n_tiles, int N, int K, long strideBe) {
  if (GATHER && (int)blockIdx.y >= *n_tiles) return;
  __shared__ __align__(16) u16 As[128 * 64];   // 16 KB
  __shared__ __align__(16) u16 Bs0[128 * 64];  // 16 KB
  __shared__ __align__(16) u16 Bs1[128 * 64];  // 16 KB
  const int tid = threadIdx.x;
  const int lane = tid & 63;
  const int wave = tid >> 6;
  const int wm = (wave >> 1) * 64;
  const int wn = (wave & 1) * 64;
  long bm;
  if (GATHER) {
    const int2 td = tdesc[blockIdx.y];
    bm = td.y;
    B0t += (long)td.x * strideBe;
    B1t += (long)td.x * strideBe;
  } else {
    bm = (long)blockIdx.y * 128;
  }
  const long bn = (long)blockIdx.x * 128;

  f32x4 acc0[4][4] = {}, acc1[4][4] = {};

  // Staging: tile = 1024 16B-chunks; LDS slot s holds (row=s>>3, chunk=c^..),
  // thread t stages slots {t, t+256, t+512, t+768} (rows r0+32i, i-invariant
  // swizzled chunk cc). Lane-linear LDS dest; swizzle on global source.
  const int r0 = tid >> 3;
  const int cc = ((tid & 7) ^ (r0 & 7)) * 8;  // swizzled element col
  const long rowstride = 32 * (long)K;        // 32 rows per slot group
  const u16* Ag[4];
  if (GATHER) {
#pragma unroll
    for (int i = 0; i < 4; i++) Ag[i] = A + (long)ridx[bm + r0 + i * 32] * K + cc;
  } else {
#pragma unroll
    for (int i = 0; i < 4; i++) Ag[i] = A + (bm + r0 + i * 32) * (long)K + cc;
  }
  const u16* B0g = B0t + (bn + r0) * (long)K + cc;
  const u16* B1g = B1t + (bn + r0) * (long)K + cc;
  const int fr = lane & 15;   // fragment row (m / n)
  const int fq = lane >> 4;   // fragment k-chunk (8 elems)

  for (int k0 = 0; k0 < K; k0 += 64) {
#pragma unroll
    for (int i = 0; i < 4; i++) {
      async_copy16(Ag[i] + k0, &As[tid * 8 + i * 2048]);
      async_copy16(B0g + i * rowstride + k0, &Bs0[tid * 8 + i * 2048]);
      async_copy16(B1g + i * rowstride + k0, &Bs1[tid * 8 + i * 2048]);
    }
    __syncthreads();
#pragma unroll
    for (int kc = 0; kc < 8; kc += 4) {  // two K=32 sub-steps
      f16x8 af[4], b0[4], b1[4];
      const int q = (fq + kc) ^ (fr & 7);  // de-swizzled chunk
#pragma unroll
      for (int i = 0; i < 4; i++) {
        af[i] = lds_frag(&As[(wm + i * 16 + fr) * 64 + q * 8]);
        b0[i] = lds_frag(&Bs0[(wn + i * 16 + fr) * 64 + q * 8]);
        b1[i] = lds_frag(&Bs1[(wn + i * 16 + fr) * 64 + q * 8]);
      }
#pragma unroll
      for (int mi = 0; mi < 4; mi++)
#pragma unroll
        for (int ni = 0; ni < 4; ni++) {
          acc0[mi][ni] = __builtin_amdgcn_mfma_f32_16x16x32_f16(af[mi], b0[ni], acc0[mi][ni], 0, 0, 0);
          acc1[mi][ni] = __builtin_amdgcn_mfma_f32_16x16x32_f16(af[mi], b1[ni], acc1[mi][ni], 0, 0, 0);
        }
    }
    __syncthreads();
  }

  const int er = (lane >> 4) * 4;  // C/D: col=lane&15, row=(lane>>4)*4+reg
  const int ec = lane & 15;
#pragma unroll
  for (int mi = 0; mi < 4; mi++)
#pragma unroll
    for (int r = 0; r < 4; r++) {
      const long row = bm + wm + mi * 16 + er + r;
#pragma unroll
      for (int ni = 0; ni < 4; ni++)
        H[row * N + bn + wn + ni * 16 + ec] =
            f2h(gelu_f(acc0[mi][ni][r]) * acc1[mi][ni][r]);
    }
}

// ---------------------------------------------------------------------------
// Out-GEMM with split-K (grid.z selects K-half): C[.,N] f32 partials.
// MOE=1: rows from tile descriptors (padded positions), expert B via tdesc.x.
// ---------------------------------------------------------------------------
template <int MOE>
__global__ __launch_bounds__(256) void gemm_out(
    const u16* __restrict__ A, const u16* __restrict__ Bt, float* __restrict__ C,
    const int2* __restrict__ tdesc, const int* __restrict__ n_tiles,
    int N, int Kfull, int Khalf, long strideBe, long strideCz) {
  if (MOE && (int)blockIdx.y >= *n_tiles) return;
  __shared__ __align__(16) u16 As[128 * 32];
  __shared__ __align__(16) u16 Bs[128 * 32];
  const int tid = threadIdx.x;
  const int lane = tid & 63;
  const int wave = tid >> 6;
  const int wm = (wave >> 1) * 64;
  const int wn = (wave & 1) * 64;
  long bm;
  if (MOE) {
    const int2 td = tdesc[blockIdx.y];
    bm = td.y;
    Bt += (long)td.x * strideBe;
  } else {
    bm = (long)blockIdx.y * 128;
  }
  const long bn = (long)blockIdx.x * 128;
  const int kbase = blockIdx.z * Khalf;
  C += (long)blockIdx.z * strideCz;

  f32x4 acc[4][4] = {};
  const int c0 = tid, c1 = tid + 256;
  const u16* Ag0 = A + (bm + (c0 >> 2)) * (long)Kfull + kbase + (c0 & 3) * 8;
  const u16* Ag1 = A + (bm + (c1 >> 2)) * (long)Kfull + kbase + (c1 & 3) * 8;
  const u16* Bg0 = Bt + (bn + (c0 >> 2)) * (long)Kfull + kbase + (c0 & 3) * 8;
  const u16* Bg1 = Bt + (bn + (c1 >> 2)) * (long)Kfull + kbase + (c1 & 3) * 8;
  u16 *As0 = &As[c0 * 8], *As1 = &As[c1 * 8];
  u16 *Bs0 = &Bs[c0 * 8], *Bs1 = &Bs[c1 * 8];
  const int fr = lane & 15;
  const int fk = (lane >> 4) * 8;

  for (int k0 = 0; k0 < Khalf; k0 += 32) {
    async_copy16(Ag0 + k0, As0);
    async_copy16(Ag1 + k0, As1);
    async_copy16(Bg0 + k0, Bs0);
    async_copy16(Bg1 + k0, Bs1);
    __syncthreads();
    f16x8 af[4], bq[4];
#pragma unroll
    for (int i = 0; i < 4; i++) af[i] = lds_frag(&As[(wm + i * 16 + fr) * 32 + fk]);
#pragma unroll
    for (int i = 0; i < 4; i++) bq[i] = lds_frag(&Bs[(wn + i * 16 + fr) * 32 + fk]);
#pragma unroll
    for (int mi = 0; mi < 4; mi++)
#pragma unroll
      for (int ni = 0; ni < 4; ni++)
        acc[mi][ni] = __builtin_amdgcn_mfma_f32_16x16x32_f16(af[mi], bq[ni], acc[mi][ni], 0, 0, 0);
    __syncthreads();
  }

  const int er = (lane >> 4) * 4;
  const int ec = lane & 15;
#pragma unroll
  for (int mi = 0; mi < 4; mi++)
#pragma unroll
    for (int r = 0; r < 4; r++) {
      const long row = bm + wm + mi * 16 + er + r;
#pragma unroll
      for (int ni = 0; ni < 4; ni++)
        C[row * N + bn + wn + ni * 16 + ec] = acc[mi][ni][r];
    }
}

// ---------------------------------------------------------------------------
// Transpose f32 [R,C] -> f16 [C,R]; dual-source variant batches over z.
// ---------------------------------------------------------------------------
__global__ __launch_bounds__(256) void transpose_cvt2(
    const float* __restrict__ s0, const float* __restrict__ s1,
    u16* __restrict__ dst, int R, int C, int zsplit) {
  __shared__ float tile[32][33];
  const int z = blockIdx.z;
  const float* src = (z < zsplit) ? s0 + (long)z * R * C
                                  : s1 + (long)(z - zsplit) * R * C;
  u16* d = dst + (long)z * R * C;
  const int c0 = blockIdx.x * 32, r0 = blockIdx.y * 32;
  const int tx = threadIdx.x & 31, ty = threadIdx.x >> 5;
#pragma unroll
  for (int i = 0; i < 32; i += 8) tile[ty + i][tx] = src[(long)(r0 + ty + i) * C + c0 + tx];
  __syncthreads();
#pragma unroll
  for (int i = 0; i < 32; i += 8) d[(long)(c0 + ty + i) * R + r0 + tx] = f2h(tile[tx][ty + i]);
}

__global__ __launch_bounds__(256) void cvt_f16(const float* __restrict__ s,
                                               u16* __restrict__ d, int n) {
  const int i = (blockIdx.x * 256 + threadIdx.x) * 4;
  if (i < n) {
    const float4 v = *(const float4*)(s + i);
    u16x4 o = {f2h(v.x), f2h(v.y), f2h(v.z), f2h(v.w)};
    *(u16x4*)(d + i) = o;
  }
}

// ---------------------------------------------------------------------------
// Router: routed_in = rms_norm(orig,ln2s) f16; softmax/top2; eidx/ewt/probs.
// ---------------------------------------------------------------------------
__global__ __launch_bounds__(256) void router_kernel(
    const float* __restrict__ orig, const float* __restrict__ pfs,
    const float* __restrict__ ln2s, const float* __restrict__ rw,
    u16* __restrict__ routed_in, int* __restrict__ eidx, float* __restrict__ ewt,
    float* __restrict__ probs_out) {
  const int t = blockIdx.x;
  const int tid = threadIdx.x;
  const float* x = orig + (long)t * DIM;
  const int d = tid * 4;
  const float4 v = *(const float4*)(x + d);
  float ss = v.x * v.x + v.y * v.y + v.z * v.z + v.w * v.w;
#pragma unroll
  for (int off = 32; off > 0; off >>= 1) ss += __shfl_down(ss, off);
  __shared__ float red[4];
  __shared__ float lred[4][8];
  if ((tid & 63) == 0) red[tid >> 6] = ss;
  __syncthreads();
  const float rs = rsqrtf((red[0] + red[1] + red[2] + red[3]) * (1.0f / DIM) + 1e-6f);

  const float4 l2 = *(const float4*)(ln2s + d);
  u16x4 ro = {f2h(v.x * rs * l2.x), f2h(v.y * rs * l2.y), f2h(v.z * rs * l2.z),
              f2h(v.w * rs * l2.w)};
  *(u16x4*)(routed_in + (long)t * DIM + d) = ro;

  const float4 pf = *(const float4*)(pfs + d);
  const float c = rs * 0.03125f;  // D^-0.5
  const float g0 = v.x * c * pf.x, g1 = v.y * c * pf.y;
  const float g2 = v.z * c * pf.z, g3 = v.w * c * pf.w;
  float lg[8];
#pragma unroll
  for (int e = 0; e < 8; e++)
    lg[e] = g0 * rw[(d + 0) * 8 + e] + g1 * rw[(d + 1) * 8 + e] +
            g2 * rw[(d + 2) * 8 + e] + g3 * rw[(d + 3) * 8 + e];
#pragma unroll
  for (int e = 0; e < 8; e++)
#pragma unroll
    for (int off = 32; off > 0; off >>= 1) lg[e] += __shfl_down(lg[e], off);
  if ((tid & 63) == 0)
#pragma unroll
    for (int e = 0; e < 8; e++) lred[tid >> 6][e] = lg[e];
  __syncthreads();
  if (tid == 0) {
    float lz[8], p[8];
    float mx = -1e30f;
#pragma unroll
    for (int e = 0; e < 8; e++) {
      lz[e] = lred[0][e] + lred[1][e] + lred[2][e] + lred[3][e];
      mx = fmaxf(mx, lz[e]);
    }
    float s = 0.0f;
#pragma unroll
    for (int e = 0; e < 8; e++) {
      p[e] = expf(lz[e] - mx);
      s += p[e];
    }
    const float invs = 1.0f / s;
#pragma unroll
    for (int e = 0; e < 8; e++) p[e] *= invs;
    int i1 = 0;
    for (int e = 1; e < 8; e++)
      if (p[e] > p[i1]) i1 = e;  // strict > keeps lowest index (lax.top_k)
    int i2 = (i1 == 0) ? 1 : 0;
    for (int e = 0; e < 8; e++)
      if (e != i1 && p[e] > p[i2]) i2 = e;
    const float wsum = p[i1] + p[i2];
    eidx[2 * t] = i1;
    eidx[2 * t + 1] = i2;
    ewt[2 * t] = p[i1] / wsum;
    ewt[2 * t + 1] = p[i2] / wsum;
    float* prow = probs_out + (long)t * 8;
    for (int e = 0; e < 8; e++) prow[e] = p[e];
  }
}

// counts[e] += #assignments; LDS hist, 8 global atomics/block
__global__ __launch_bounds__(256) void bucket_count(const int* __restrict__ eidx,
                                                    int* __restrict__ counts) {
  __shared__ int lcnt[8];
  const int tid = threadIdx.x;
  if (tid < 8) lcnt[tid] = 0;
  __syncthreads();
  const int t = blockIdx.x * 256 + tid;
  atomicAdd(&lcnt[eidx[2 * t]], 1);
  atomicAdd(&lcnt[eidx[2 * t + 1]], 1);
  __syncthreads();
  if (tid < 8) atomicAdd(&counts[tid], lcnt[tid]);
}

__global__ void setup_tiles(const int* __restrict__ counts, int* __restrict__ poffset,
                            int2* __restrict__ tdesc, int* __restrict__ n_tiles) {
  if (threadIdx.x == 0 && blockIdx.x == 0) {
    int cur = 0, nt = 0;
    for (int e = 0; e < NEXP; e++) {
      poffset[e] = cur;
      const int ntile = (counts[e] + 127) >> 7;
      for (int i = 0; i < ntile; i++) {
        int2 d;
        d.x = e;
        d.y = cur + i * 128;
        tdesc[nt++] = d;
      }
      cur += ntile * 128;
    }
    n_tiles[0] = nt;
  }
}

__global__ __launch_bounds__(256) void bucket_scatter(
    const int* __restrict__ eidx, const int* __restrict__ poffset,
    int* __restrict__ cursors, int* __restrict__ ridx, int* __restrict__ pos) {
  __shared__ int lcnt[8], base[8];
  const int tid = threadIdx.x;
  if (tid < 8) lcnt[tid] = 0;
  __syncthreads();
  const int t = blockIdx.x * 256 + tid;
  const int e0 = eidx[2 * t], e1 = eidx[2 * t + 1];
  const int r0 = atomicAdd(&lcnt[e0], 1);
  const int r1 = atomicAdd(&lcnt[e1], 1);
  __syncthreads();
  if (tid < 8) base[tid] = atomicAdd(&cursors[tid], lcnt[tid]);
  __syncthreads();
  const int p0 = poffset[e0] + base[e0] + r0;
  const int p1 = poffset[e1] + base[e1] + r1;
  ridx[p0] = t;
  ridx[p1] = t;
  pos[2 * t] = p0;
  pos[2 * t + 1] = p1;
}

__global__ __launch_bounds__(256) void lb_reduce(const float* __restrict__ probs,
                                                 const int* __restrict__ counts,
                                                 float* __restrict__ out) {
  const int tid = threadIdx.x;
  float psum[8] = {};
  for (int tt = 0; tt < 16; tt++) {
    const long t = (long)tid * 16 + tt;
    const float4* pp = (const float4*)(probs + t * 8);
    const float4 p0 = pp[0], p1 = pp[1];
    psum[0] += p0.x; psum[1] += p0.y; psum[2] += p0.z; psum[3] += p0.w;
    psum[4] += p1.x; psum[5] += p1.y; psum[6] += p1.z; psum[7] += p1.w;
  }
#pragma unroll
  for (int e = 0; e < 8; e++)
#pragma unroll
    for (int off = 32; off > 0; off >>= 1) psum[e] += __shfl_down(psum[e], off);
  __shared__ float sp[4][8];
  if ((tid & 63) == 0)
#pragma unroll
    for (int e = 0; e < 8; e++) sp[tid >> 6][e] = psum[e];
  __syncthreads();
  if (tid == 0) {
    float loss = 0.0f;
#pragma unroll
    for (int e = 0; e < 8; e++) {
      const float fp = (sp[0][e] + sp[1][e] + sp[2][e] + sp[3][e]) / 4096.0f;
      const float ft = (float)counts[e] / (4096.0f * 2.0f);
      loss += ft * fp;
    }
    out[0] = 8.0f * loss;
  }
}

// out = rms_norm(x0+x1, scale)  (shared path; sums split-K partials)
__global__ __launch_bounds__(256) void rms_norm_out(const float* __restrict__ x,
                                                    const float* __restrict__ scale,
                                                    float* __restrict__ out) {
  const int t = blockIdx.x;
  const int tid = threadIdx.x;
  const long base = (long)t * DIM + tid * 4;
  const float4 a = *(const float4*)(x + base);
  const float4 b = *(const float4*)(x + base + (long)T_TOK * DIM);
  float4 v;
  v.x = a.x + b.x; v.y = a.y + b.y; v.z = a.z + b.z; v.w = a.w + b.w;
  float ss = v.x * v.x + v.y * v.y + v.z * v.z + v.w * v.w;
#pragma unroll
  for (int off = 32; off > 0; off >>= 1) ss += __shfl_down(ss, off);
  __shared__ float red[4];
  if ((tid & 63) == 0) red[tid >> 6] = ss;
  __syncthreads();
  const float rs = rsqrtf((red[0] + red[1] + red[2] + red[3]) * (1.0f / DIM) + 1e-6f);
  const float4 sc = *(const float4*)(scale + tid * 4);
  float4 o;
  o.x = v.x * rs * sc.x;
  o.y = v.y * rs * sc.y;
  o.z = v.z * rs * sc.z;
  o.w = v.w * rs * sc.w;
  *(float4*)(out + base) = o;
}

// routed combine (sums split-K partials): v = w0*(H0+H1)[p0] + w1*(H0+H1)[p1]
__global__ __launch_bounds__(256) void combine_norm(
    const float* __restrict__ Hout, const int* __restrict__ pos,
    const float* __restrict__ ewt, const float* __restrict__ scale,
    float* __restrict__ out) {
  const int t = blockIdx.x;
  const int tid = threadIdx.x;
  const float w0 = ewt[2 * t], w1 = ewt[2 * t + 1];
  const long p0 = pos[2 * t], p1 = pos[2 * t + 1];
  const int d = tid * 4;
  const long SK = (long)HROWS * DIM;
  const float4 a0 = *(const float4*)(Hout + p0 * DIM + d);
  const float4 a1 = *(const float4*)(Hout + SK + p0 * DIM + d);
  const float4 b0 = *(const float4*)(Hout + p1 * DIM + d);
  const float4 b1 = *(const float4*)(Hout + SK + p1 * DIM + d);
  float4 v;
  v.x = w0 * (a0.x + a1.x) + w1 * (b0.x + b1.x);
  v.y = w0 * (a0.y + a1.y) + w1 * (b0.y + b1.y);
  v.z = w0 * (a0.z + a1.z) + w1 * (b0.z + b1.z);
  v.w = w0 * (a0.w + a1.w) + w1 * (b0.w + b1.w);
  float ss = v.x * v.x + v.y * v.y + v.z * v.z + v.w * v.w;
#pragma unroll
  for (int off = 32; off > 0; off >>= 1) ss += __shfl_down(ss, off);
  __shared__ float red[4];
  if ((tid & 63) == 0) red[tid >> 6] = ss;
  __syncthreads();
  const float rs = rsqrtf((red[0] + red[1] + red[2] + red[3]) * (1.0f / DIM) + 1e-6f);
  const float4 sc = *(const float4*)(scale + d);
  const long base = (long)t * DIM + d;
  float4 o = *(float4*)(out + base);
  o.x += v.x * rs * sc.x;
  o.y += v.y * rs * sc.y;
  o.z += v.z * rs * sc.z;
  o.w += v.w * rs * sc.w;
  *(float4*)(out + base) = o;
}

// ---------------------------------------------------------------------------
extern "C" void kernel_launch(void* const* d_in, const int* in_sizes, int n_in,
                              void* d_out, int out_size, void* d_ws, size_t ws_size,
                              hipStream_t stream) {
  (void)in_sizes; (void)n_in; (void)out_size; (void)ws_size;
  const float* inputs   = (const float*)d_in[0];
  const float* orig     = (const float*)d_in[1];
  const float* pfs      = (const float*)d_in[2];
  const float* ln2s     = (const float*)d_in[3];
  const float* post1    = (const float*)d_in[4];
  const float* post2    = (const float*)d_in[5];
  const float* router_w = (const float*)d_in[6];
  const float* e_wi0    = (const float*)d_in[7];
  const float* e_wi1    = (const float*)d_in[8];
  const float* e_wo     = (const float*)d_in[9];
  const float* s_wi0    = (const float*)d_in[10];
  const float* s_wi1    = (const float*)d_in[11];
  const float* s_wo     = (const float*)d_in[12];

  char* ws = (char*)d_ws;
  size_t o = 0;
  auto alloc = [&](size_t bytes) -> void* {
    void* p = ws + o;
    o += (bytes + 255) & ~(size_t)255;
    return p;
  };
  u16* s_wi_t  = (u16*)alloc((size_t)2 * FDIM * DIM * 2);        // [2][F,D]
  u16* s_wo_t  = (u16*)alloc((size_t)DIM * FDIM * 2);            // [D,F]
  u16* e_wi_t  = (u16*)alloc((size_t)2 * NEXP * MDIM * DIM * 2); // [2][E,M,D]
  u16* e_wo_t  = (u16*)alloc((size_t)NEXP * DIM * MDIM * 2);     // [E,D,M]
  u16* x_sh    = (u16*)alloc((size_t)T_TOK * DIM * 2);
  u16* routed  = (u16*)alloc((size_t)T_TOK * DIM * 2);
  float* probs = (float*)alloc((size_t)T_TOK * 8 * 4);
  int* eidx    = (int*)alloc((size_t)T_TOK * 2 * 4);
  float* ewt   = (float*)alloc((size_t)T_TOK * 2 * 4);
  int* pos     = (int*)alloc((size_t)T_TOK * 2 * 4);
  int* imeta   = (int*)alloc(256);           // [0..7] counts, [8..15] cursors
  int* poffset = (int*)alloc(64);
  int* n_tiles = (int*)alloc(64);
  int2* tdesc  = (int2*)alloc(MAXTILES * 8);
  int* ridx    = (int*)alloc((size_t)HROWS * 4);
  float* racc  = (float*)alloc((size_t)2 * T_TOK * DIM * 4);     // split-K partials
  u16* Hs      = (u16*)alloc((size_t)T_TOK * FDIM * 2);          // gated h (shared)
  u16* H       = (u16*)alloc((size_t)HROWS * MDIM * 2);          // gated h (routed)
  float* Hout  = (float*)alloc((size_t)2 * HROWS * DIM * 4);     // split-K partials

  int* counts = imeta;
  int* cursors = imeta + 8;

  hipMemsetAsync(imeta, 0, 64, stream);
  hipMemsetAsync(ridx, 0, (size_t)HROWS * 4, stream);

  // ---- weight transposes (f32 -> f16 B^T layouts), 4 launches ----
  transpose_cvt2<<<dim3(FDIM / 32, DIM / 32, 2), 256, 0, stream>>>(
      s_wi0, s_wi1, s_wi_t, DIM, FDIM, 1);
  transpose_cvt2<<<dim3(DIM / 32, FDIM / 32, 1), 256, 0, stream>>>(
      s_wo, s_wo, s_wo_t, FDIM, DIM, 1);
  transpose_cvt2<<<dim3(MDIM / 32, DIM / 32, 16), 256, 0, stream>>>(
      e_wi0, e_wi1, e_wi_t, DIM, MDIM, 8);
  transpose_cvt2<<<dim3(DIM / 32, MDIM / 32, 8), 256, 0, stream>>>(
      e_wo, e_wo, e_wo_t, MDIM, DIM, 8);

  cvt_f16<<<T_TOK * DIM / 4 / 256, 256, 0, stream>>>(inputs, x_sh, T_TOK * DIM);
  router_kernel<<<T_TOK, 256, 0, stream>>>(orig, pfs, ln2s, router_w, routed, eidx, ewt, probs);

  // ---- bucketing ----
  bucket_count<<<16, 256, 0, stream>>>(eidx, counts);
  setup_tiles<<<1, 64, 0, stream>>>(counts, poffset, tdesc, n_tiles);
  bucket_scatter<<<16, 256, 0, stream>>>(eidx, poffset, cursors, ridx, pos);

  // ---- shared expert path ----
  gemm_gated<0><<<dim3(FDIM / 128, T_TOK / 128, 1), 256, 0, stream>>>(
      x_sh, s_wi_t, s_wi_t + (size_t)FDIM * DIM, Hs, nullptr, nullptr, nullptr,
      FDIM, DIM, 0);
  gemm_out<0><<<dim3(DIM / 128, T_TOK / 128, 2), 256, 0, stream>>>(
      Hs, s_wo_t, racc, nullptr, nullptr, DIM, FDIM, FDIM / 2, 0, (long)T_TOK * DIM);
  rms_norm_out<<<T_TOK, 256, 0, stream>>>(racc, post1, (float*)d_out);

  // ---- routed experts: sparse gated GEMM + split-K out-GEMM ----
  gemm_gated<1><<<dim3(MDIM / 128, MAXTILES, 1), 256, 0, stream>>>(
      routed, e_wi_t, e_wi_t + (size_t)NEXP * MDIM * DIM, H, ridx, tdesc, n_tiles,
      MDIM, DIM, (long)MDIM * DIM);
  gemm_out<1><<<dim3(DIM / 128, MAXTILES, 2), 256, 0, stream>>>(
      H, e_wo_t, Hout, tdesc, n_tiles, DIM, MDIM, MDIM / 2,
      (long)DIM * MDIM, (long)HROWS * DIM);
  combine_norm<<<T_TOK, 256, 0, stream>>>(Hout, pos, ewt, post2, (float*)d_out);

  lb_reduce<<<1, 256, 0, stream>>>(probs, counts, (float*)d_out + (size_t)T_TOK * DIM);
}

// Round 6
// 434.412 us; speedup vs baseline: 3.2507x; 1.0305x over previous
//
#include <hip/hip_runtime.h>
#include <stdint.h>

// ---------------------------------------------------------------------------
// Gemma4 MoE block on gfx950. FP16 MFMA (16x16x32) GEMMs, f32 accumulation.
// R2: sparse top-2 routed experts (tile-padded bucketing + grouped GEMMs).
// R4: gated dual-GEMM, 256 thr, dual acc, BK=64, XOR source swizzle (R5: 0
//     bank conflicts confirmed).
// R6: dispatch merging — ONE in-GEMM launch (shared+routed), ONE out-GEMM
//     launch (shared+routed, BK=64+swizzle, split-K), fused final_norm
//     (rms(shared)+combine-rms(routed), single d_out write), cvt folded into
//     router. 13 -> 10 launches; tails overlap across phases.
// ---------------------------------------------------------------------------

typedef unsigned short u16;
typedef u16 u16x4 __attribute__((ext_vector_type(4)));
typedef u16 u16x8 __attribute__((ext_vector_type(8)));
typedef _Float16 f16x8 __attribute__((ext_vector_type(8)));
typedef float f32x4 __attribute__((ext_vector_type(4)));
typedef __attribute__((address_space(1))) void* as1_vp;
typedef __attribute__((address_space(3))) void* as3_vp;

#define T_TOK 4096
#define DIM   1024
#define FDIM  2048
#define MDIM  1024
#define NEXP  8
#define MAXTILES 72            // sum ceil(cnt_e/128) <= 64 + 7, padded
#define HROWS (MAXTILES * 128) // 9216 padded assignment rows

__device__ __forceinline__ u16 f2h(float f) {
  _Float16 h = (_Float16)f;
  return __builtin_bit_cast(u16, h);
}
__device__ __forceinline__ float h2f(u16 u) {
  return (float)__builtin_bit_cast(_Float16, u);
}
// tanh-approx gelu rewritten exactly as x*sigmoid(2y): cheap __expf + div
__device__ __forceinline__ float gelu_f(float x) {
  const float y2 = x * (1.5957691216f + 0.0713548163f * x * x);
  return x / (1.0f + __expf(-y2));
}
__device__ __forceinline__ void async_copy16(const void* g, void* l) {
  __builtin_amdgcn_global_load_lds((as1_vp)(uintptr_t)g,
                                   (as3_vp)(uint32_t)(uintptr_t)l, 16, 0, 0);
}
__device__ __forceinline__ f16x8 lds_frag(const u16* p) {
  return __builtin_bit_cast(f16x8, *(const u16x8*)p);
}

// ---------------------------------------------------------------------------
// Merged gated dual-GEMM (shared + routed in ONE dispatch).
// H = gelu(A@B0) * (A@B1), f16. 256 thr / 4 waves (2x2 of 64x64), dual acc
// per wave (in-register gelu*mul). BK=64, 48 KB LDS, XOR source swizzle.
// blockIdx.y < 32: shared (A=x_sh, N=FDIM, all 16 x-blocks).
// blockIdx.y >= 32: routed tile (gather rows via ridx, N=MDIM, x < 8).
// K = DIM = 1024 for both.
// ---------------------------------------------------------------------------
__global__ __launch_bounds__(256, 2) void gemm_in(
    const u16* __restrict__ xs, const u16* __restrict__ swi_t,
    const u16* __restrict__ routed, const u16* __restrict__ ewi_t,
    u16* __restrict__ Hs, u16* __restrict__ Hr,
    const int* __restrict__ ridx, const int2* __restrict__ tdesc,
    const int* __restrict__ n_tiles) {
  const int yb = (int)blockIdx.y;
  const u16 *A, *B0t, *B1t;
  u16* H;
  int N;
  long bm;
  bool gather;
  if (yb < 32) {
    bm = (long)yb * 128;
    A = xs;
    B0t = swi_t;
    B1t = swi_t + (size_t)FDIM * DIM;
    H = Hs;
    N = FDIM;
    gather = false;
  } else {
    const int ty = yb - 32;
    if (ty >= *n_tiles) return;
    if ((int)blockIdx.x >= MDIM / 128) return;
    const int2 td = tdesc[ty];
    bm = td.y;
    A = routed;
    B0t = ewi_t + (long)td.x * MDIM * DIM;
    B1t = ewi_t + (size_t)NEXP * MDIM * DIM + (long)td.x * MDIM * DIM;
    H = Hr;
    N = MDIM;
    gather = true;
  }
  __shared__ __align__(16) u16 As[128 * 64];   // 16 KB
  __shared__ __align__(16) u16 Bs0[128 * 64];  // 16 KB
  __shared__ __align__(16) u16 Bs1[128 * 64];  // 16 KB
  const int tid = threadIdx.x;
  const int lane = tid & 63;
  const int wave = tid >> 6;
  const int wm = (wave >> 1) * 64;
  const int wn = (wave & 1) * 64;
  const long bn = (long)blockIdx.x * 128;

  f32x4 acc0[4][4] = {}, acc1[4][4] = {};

  // Staging: slot s = (row, swizzled chunk); lane-linear LDS dest, swizzle on
  // global source index (validated R5: SQ_LDS_BANK_CONFLICT = 0).
  const int r0 = tid >> 3;
  const int cc = ((tid & 7) ^ (r0 & 7)) * 8;
  const long rowstride = 32 * (long)DIM;
  const u16* Ag[4];
  if (gather) {
#pragma unroll
    for (int i = 0; i < 4; i++) Ag[i] = A + (long)ridx[bm + r0 + i * 32] * DIM + cc;
  } else {
#pragma unroll
    for (int i = 0; i < 4; i++) Ag[i] = A + (bm + r0 + i * 32) * (long)DIM + cc;
  }
  const u16* B0g = B0t + (bn + r0) * (long)DIM + cc;
  const u16* B1g = B1t + (bn + r0) * (long)DIM + cc;
  const int fr = lane & 15;
  const int fq = lane >> 4;

  for (int k0 = 0; k0 < DIM; k0 += 64) {
#pragma unroll
    for (int i = 0; i < 4; i++) {
      async_copy16(Ag[i] + k0, &As[tid * 8 + i * 2048]);
      async_copy16(B0g + i * rowstride + k0, &Bs0[tid * 8 + i * 2048]);
      async_copy16(B1g + i * rowstride + k0, &Bs1[tid * 8 + i * 2048]);
    }
    __syncthreads();
#pragma unroll
    for (int kc = 0; kc < 8; kc += 4) {
      f16x8 af[4], b0[4], b1[4];
      const int q = (fq + kc) ^ (fr & 7);
#pragma unroll
      for (int i = 0; i < 4; i++) {
        af[i] = lds_frag(&As[(wm + i * 16 + fr) * 64 + q * 8]);
        b0[i] = lds_frag(&Bs0[(wn + i * 16 + fr) * 64 + q * 8]);
        b1[i] = lds_frag(&Bs1[(wn + i * 16 + fr) * 64 + q * 8]);
      }
#pragma unroll
      for (int mi = 0; mi < 4; mi++)
#pragma unroll
        for (int ni = 0; ni < 4; ni++) {
          acc0[mi][ni] = __builtin_amdgcn_mfma_f32_16x16x32_f16(af[mi], b0[ni], acc0[mi][ni], 0, 0, 0);
          acc1[mi][ni] = __builtin_amdgcn_mfma_f32_16x16x32_f16(af[mi], b1[ni], acc1[mi][ni], 0, 0, 0);
        }
    }
    __syncthreads();
  }

  const int er = (lane >> 4) * 4;  // C/D: col=lane&15, row=(lane>>4)*4+reg
  const int ec = lane & 15;
#pragma unroll
  for (int mi = 0; mi < 4; mi++)
#pragma unroll
    for (int r = 0; r < 4; r++) {
      const long row = bm + wm + mi * 16 + er + r;
#pragma unroll
      for (int ni = 0; ni < 4; ni++)
        H[row * N + bn + wn + ni * 16 + ec] =
            f2h(gelu_f(acc0[mi][ni][r]) * acc1[mi][ni][r]);
    }
}

// ---------------------------------------------------------------------------
// Merged out-GEMM (shared + routed, split-K via grid.z), BK=64 + swizzle.
// y<32: shared A=Hs (Kfull=FDIM, Khalf=FDIM/2), C=racc partials.
// y>=32: routed tile (rows = padded positions, Kfull=MDIM, Khalf=MDIM/2),
//        C=Hout partials. N = DIM for both.
// ---------------------------------------------------------------------------
__global__ __launch_bounds__(256) void gemm_out2(
    const u16* __restrict__ Hs, const u16* __restrict__ swo_t,
    float* __restrict__ racc, const u16* __restrict__ Hr,
    const u16* __restrict__ ewo_t, float* __restrict__ Hout,
    const int2* __restrict__ tdesc, const int* __restrict__ n_tiles) {
  const int yb = (int)blockIdx.y;
  const u16 *A, *Bt;
  float* C;
  long bm;
  int Kfull, Khalf;
  if (yb < 32) {
    bm = (long)yb * 128;
    A = Hs;
    Bt = swo_t;
    Kfull = FDIM;
    Khalf = FDIM / 2;
    C = racc + (long)blockIdx.z * T_TOK * DIM;
  } else {
    const int ty = yb - 32;
    if (ty >= *n_tiles) return;
    const int2 td = tdesc[ty];
    bm = td.y;
    A = Hr;
    Bt = ewo_t + (long)td.x * DIM * MDIM;
    Kfull = MDIM;
    Khalf = MDIM / 2;
    C = Hout + (long)blockIdx.z * HROWS * DIM;
  }
  __shared__ __align__(16) u16 As[128 * 64];  // 16 KB
  __shared__ __align__(16) u16 Bs[128 * 64];  // 16 KB
  const int tid = threadIdx.x;
  const int lane = tid & 63;
  const int wave = tid >> 6;
  const int wm = (wave >> 1) * 64;
  const int wn = (wave & 1) * 64;
  const long bn = (long)blockIdx.x * 128;
  const int kbase = blockIdx.z * Khalf;

  f32x4 acc[4][4] = {};
  const int r0 = tid >> 3;
  const int cc = ((tid & 7) ^ (r0 & 7)) * 8;
  const long rowstride = 32 * (long)Kfull;
  const u16* Ag[4];
#pragma unroll
  for (int i = 0; i < 4; i++) Ag[i] = A + (bm + r0 + i * 32) * (long)Kfull + kbase + cc;
  const u16* Bg = Bt + (bn + r0) * (long)Kfull + kbase + cc;
  const int fr = lane & 15;
  const int fq = lane >> 4;

  for (int k0 = 0; k0 < Khalf; k0 += 64) {
#pragma unroll
    for (int i = 0; i < 4; i++) {
      async_copy16(Ag[i] + k0, &As[tid * 8 + i * 2048]);
      async_copy16(Bg + i * rowstride + k0, &Bs[tid * 8 + i * 2048]);
    }
    __syncthreads();
#pragma unroll
    for (int kc = 0; kc < 8; kc += 4) {
      f16x8 af[4], bq[4];
      const int q = (fq + kc) ^ (fr & 7);
#pragma unroll
      for (int i = 0; i < 4; i++) {
        af[i] = lds_frag(&As[(wm + i * 16 + fr) * 64 + q * 8]);
        bq[i] = lds_frag(&Bs[(wn + i * 16 + fr) * 64 + q * 8]);
      }
#pragma unroll
      for (int mi = 0; mi < 4; mi++)
#pragma unroll
        for (int ni = 0; ni < 4; ni++)
          acc[mi][ni] = __builtin_amdgcn_mfma_f32_16x16x32_f16(af[mi], bq[ni], acc[mi][ni], 0, 0, 0);
    }
    __syncthreads();
  }

  const int er = (lane >> 4) * 4;
  const int ec = lane & 15;
#pragma unroll
  for (int mi = 0; mi < 4; mi++)
#pragma unroll
    for (int r = 0; r < 4; r++) {
      const long row = bm + wm + mi * 16 + er + r;
#pragma unroll
      for (int ni = 0; ni < 4; ni++)
        C[row * DIM + bn + wn + ni * 16 + ec] = acc[mi][ni][r];
    }
}

// ---------------------------------------------------------------------------
// Transpose f32 [R,C] -> f16 [C,R]; dual-source variant batches over z.
// ---------------------------------------------------------------------------
__global__ __launch_bounds__(256) void transpose_cvt2(
    const float* __restrict__ s0, const float* __restrict__ s1,
    u16* __restrict__ dst, int R, int C, int zsplit) {
  __shared__ float tile[32][33];
  const int z = blockIdx.z;
  const float* src = (z < zsplit) ? s0 + (long)z * R * C
                                  : s1 + (long)(z - zsplit) * R * C;
  u16* d = dst + (long)z * R * C;
  const int c0 = blockIdx.x * 32, r0 = blockIdx.y * 32;
  const int tx = threadIdx.x & 31, ty = threadIdx.x >> 5;
#pragma unroll
  for (int i = 0; i < 32; i += 8) tile[ty + i][tx] = src[(long)(r0 + ty + i) * C + c0 + tx];
  __syncthreads();
#pragma unroll
  for (int i = 0; i < 32; i += 8) d[(long)(c0 + ty + i) * R + r0 + tx] = f2h(tile[tx][ty + i]);
}

// ---------------------------------------------------------------------------
// Router (+ folded x_sh f16 conversion): routed_in = rms_norm(orig,ln2s) f16;
// softmax/top2; eidx/ewt/probs. One block per token. No atomics.
// ---------------------------------------------------------------------------
__global__ __launch_bounds__(256) void router_kernel(
    const float* __restrict__ orig, const float* __restrict__ inputs,
    const float* __restrict__ pfs, const float* __restrict__ ln2s,
    const float* __restrict__ rw, u16* __restrict__ routed_in,
    u16* __restrict__ x_sh, int* __restrict__ eidx, float* __restrict__ ewt,
    float* __restrict__ probs_out) {
  const int t = blockIdx.x;
  const int tid = threadIdx.x;
  const int d = tid * 4;
  // folded cvt: inputs row -> f16
  {
    const float4 xi = *(const float4*)(inputs + (long)t * DIM + d);
    u16x4 xo = {f2h(xi.x), f2h(xi.y), f2h(xi.z), f2h(xi.w)};
    *(u16x4*)(x_sh + (long)t * DIM + d) = xo;
  }
  const float4 v = *(const float4*)(orig + (long)t * DIM + d);
  float ss = v.x * v.x + v.y * v.y + v.z * v.z + v.w * v.w;
#pragma unroll
  for (int off = 32; off > 0; off >>= 1) ss += __shfl_down(ss, off);
  __shared__ float red[4];
  __shared__ float lred[4][8];
  if ((tid & 63) == 0) red[tid >> 6] = ss;
  __syncthreads();
  const float rs = rsqrtf((red[0] + red[1] + red[2] + red[3]) * (1.0f / DIM) + 1e-6f);

  const float4 l2 = *(const float4*)(ln2s + d);
  u16x4 ro = {f2h(v.x * rs * l2.x), f2h(v.y * rs * l2.y), f2h(v.z * rs * l2.z),
              f2h(v.w * rs * l2.w)};
  *(u16x4*)(routed_in + (long)t * DIM + d) = ro;

  const float4 pf = *(const float4*)(pfs + d);
  const float c = rs * 0.03125f;  // D^-0.5
  const float g0 = v.x * c * pf.x, g1 = v.y * c * pf.y;
  const float g2 = v.z * c * pf.z, g3 = v.w * c * pf.w;
  float lg[8];
#pragma unroll
  for (int e = 0; e < 8; e++)
    lg[e] = g0 * rw[(d + 0) * 8 + e] + g1 * rw[(d + 1) * 8 + e] +
            g2 * rw[(d + 2) * 8 + e] + g3 * rw[(d + 3) * 8 + e];
#pragma unroll
  for (int e = 0; e < 8; e++)
#pragma unroll
    for (int off = 32; off > 0; off >>= 1) lg[e] += __shfl_down(lg[e], off);
  if ((tid & 63) == 0)
#pragma unroll
    for (int e = 0; e < 8; e++) lred[tid >> 6][e] = lg[e];
  __syncthreads();
  if (tid == 0) {
    float lz[8], p[8];
    float mx = -1e30f;
#pragma unroll
    for (int e = 0; e < 8; e++) {
      lz[e] = lred[0][e] + lred[1][e] + lred[2][e] + lred[3][e];
      mx = fmaxf(mx, lz[e]);
    }
    float s = 0.0f;
#pragma unroll
    for (int e = 0; e < 8; e++) {
      p[e] = expf(lz[e] - mx);
      s += p[e];
    }
    const float invs = 1.0f / s;
#pragma unroll
    for (int e = 0; e < 8; e++) p[e] *= invs;
    int i1 = 0;
    for (int e = 1; e < 8; e++)
      if (p[e] > p[i1]) i1 = e;  // strict > keeps lowest index (lax.top_k)
    int i2 = (i1 == 0) ? 1 : 0;
    for (int e = 0; e < 8; e++)
      if (e != i1 && p[e] > p[i2]) i2 = e;
    const float wsum = p[i1] + p[i2];
    eidx[2 * t] = i1;
    eidx[2 * t + 1] = i2;
    ewt[2 * t] = p[i1] / wsum;
    ewt[2 * t + 1] = p[i2] / wsum;
    float* prow = probs_out + (long)t * 8;
    for (int e = 0; e < 8; e++) prow[e] = p[e];
  }
}

// counts[e] += #assignments; LDS hist, 8 global atomics/block
__global__ __launch_bounds__(256) void bucket_count(const int* __restrict__ eidx,
                                                    int* __restrict__ counts) {
  __shared__ int lcnt[8];
  const int tid = threadIdx.x;
  if (tid < 8) lcnt[tid] = 0;
  __syncthreads();
  const int t = blockIdx.x * 256 + tid;
  atomicAdd(&lcnt[eidx[2 * t]], 1);
  atomicAdd(&lcnt[eidx[2 * t + 1]], 1);
  __syncthreads();
  if (tid < 8) atomicAdd(&counts[tid], lcnt[tid]);
}

__global__ void setup_tiles(const int* __restrict__ counts, int* __restrict__ poffset,
                            int2* __restrict__ tdesc, int* __restrict__ n_tiles) {
  if (threadIdx.x == 0 && blockIdx.x == 0) {
    int cur = 0, nt = 0;
    for (int e = 0; e < NEXP; e++) {
      poffset[e] = cur;
      const int ntile = (counts[e] + 127) >> 7;
      for (int i = 0; i < ntile; i++) {
        int2 d;
        d.x = e;
        d.y = cur + i * 128;
        tdesc[nt++] = d;
      }
      cur += ntile * 128;
    }
    n_tiles[0] = nt;
  }
}

__global__ __launch_bounds__(256) void bucket_scatter(
    const int* __restrict__ eidx, const int* __restrict__ poffset,
    int* __restrict__ cursors, int* __restrict__ ridx, int* __restrict__ pos) {
  __shared__ int lcnt[8], base[8];
  const int tid = threadIdx.x;
  if (tid < 8) lcnt[tid] = 0;
  __syncthreads();
  const int t = blockIdx.x * 256 + tid;
  const int e0 = eidx[2 * t], e1 = eidx[2 * t + 1];
  const int r0 = atomicAdd(&lcnt[e0], 1);
  const int r1 = atomicAdd(&lcnt[e1], 1);
  __syncthreads();
  if (tid < 8) base[tid] = atomicAdd(&cursors[tid], lcnt[tid]);
  __syncthreads();
  const int p0 = poffset[e0] + base[e0] + r0;
  const int p1 = poffset[e1] + base[e1] + r1;
  ridx[p0] = t;
  ridx[p1] = t;
  pos[2 * t] = p0;
  pos[2 * t + 1] = p1;
}

__global__ __launch_bounds__(256) void lb_reduce(const float* __restrict__ probs,
                                                 const int* __restrict__ counts,
                                                 float* __restrict__ out) {
  const int tid = threadIdx.x;
  float psum[8] = {};
  for (int tt = 0; tt < 16; tt++) {
    const long t = (long)tid * 16 + tt;
    const float4* pp = (const float4*)(probs + t * 8);
    const float4 p0 = pp[0], p1 = pp[1];
    psum[0] += p0.x; psum[1] += p0.y; psum[2] += p0.z; psum[3] += p0.w;
    psum[4] += p1.x; psum[5] += p1.y; psum[6] += p1.z; psum[7] += p1.w;
  }
#pragma unroll
  for (int e = 0; e < 8; e++)
#pragma unroll
    for (int off = 32; off > 0; off >>= 1) psum[e] += __shfl_down(psum[e], off);
  __shared__ float sp[4][8];
  if ((tid & 63) == 0)
#pragma unroll
    for (int e = 0; e < 8; e++) sp[tid >> 6][e] = psum[e];
  __syncthreads();
  if (tid == 0) {
    float loss = 0.0f;
#pragma unroll
    for (int e = 0; e < 8; e++) {
      const float fp = (sp[0][e] + sp[1][e] + sp[2][e] + sp[3][e]) / 4096.0f;
      const float ft = (float)counts[e] / (4096.0f * 2.0f);
      loss += ft * fp;
    }
    out[0] = 8.0f * loss;
  }
}

// ---------------------------------------------------------------------------
// Final epilogue: out = rms(shared_partials, post1) + rms(combined, post2).
// Single d_out write; sums split-K partials for both paths.
// ---------------------------------------------------------------------------
__global__ __launch_bounds__(256) void final_norm(
    const float* __restrict__ racc, const float* __restrict__ Hout,
    const int* __restrict__ pos, const float* __restrict__ ewt,
    const float* __restrict__ post1, const float* __restrict__ post2,
    float* __restrict__ out) {
  const int t = blockIdx.x;
  const int tid = threadIdx.x;
  const int d = tid * 4;
  const long base = (long)t * DIM + d;
  // shared path
  const float4 a = *(const float4*)(racc + base);
  const float4 b = *(const float4*)(racc + base + (long)T_TOK * DIM);
  float4 vs;
  vs.x = a.x + b.x; vs.y = a.y + b.y; vs.z = a.z + b.z; vs.w = a.w + b.w;
  // routed path
  const float w0 = ewt[2 * t], w1 = ewt[2 * t + 1];
  const long p0 = pos[2 * t], p1 = pos[2 * t + 1];
  const long SK = (long)HROWS * DIM;
  const float4 a0 = *(const float4*)(Hout + p0 * DIM + d);
  const float4 a1 = *(const float4*)(Hout + SK + p0 * DIM + d);
  const float4 b0 = *(const float4*)(Hout + p1 * DIM + d);
  const float4 b1 = *(const float4*)(Hout + SK + p1 * DIM + d);
  float4 vr;
  vr.x = w0 * (a0.x + a1.x) + w1 * (b0.x + b1.x);
  vr.y = w0 * (a0.y + a1.y) + w1 * (b0.y + b1.y);
  vr.z = w0 * (a0.z + a1.z) + w1 * (b0.z + b1.z);
  vr.w = w0 * (a0.w + a1.w) + w1 * (b0.w + b1.w);
  float ss = vs.x * vs.x + vs.y * vs.y + vs.z * vs.z + vs.w * vs.w;
  float sr = vr.x * vr.x + vr.y * vr.y + vr.z * vr.z + vr.w * vr.w;
#pragma unroll
  for (int off = 32; off > 0; off >>= 1) {
    ss += __shfl_down(ss, off);
    sr += __shfl_down(sr, off);
  }
  __shared__ float reds[4], redr[4];
  if ((tid & 63) == 0) {
    reds[tid >> 6] = ss;
    redr[tid >> 6] = sr;
  }
  __syncthreads();
  const float rss = rsqrtf((reds[0] + reds[1] + reds[2] + reds[3]) * (1.0f / DIM) + 1e-6f);
  const float rsr = rsqrtf((redr[0] + redr[1] + redr[2] + redr[3]) * (1.0f / DIM) + 1e-6f);
  const float4 s1 = *(const float4*)(post1 + d);
  const float4 s2 = *(const float4*)(post2 + d);
  float4 o;
  o.x = vs.x * rss * s1.x + vr.x * rsr * s2.x;
  o.y = vs.y * rss * s1.y + vr.y * rsr * s2.y;
  o.z = vs.z * rss * s1.z + vr.z * rsr * s2.z;
  o.w = vs.w * rss * s1.w + vr.w * rsr * s2.w;
  *(float4*)(out + base) = o;
}

// ---------------------------------------------------------------------------
extern "C" void kernel_launch(void* const* d_in, const int* in_sizes, int n_in,
                              void* d_out, int out_size, void* d_ws, size_t ws_size,
                              hipStream_t stream) {
  (void)in_sizes; (void)n_in; (void)out_size; (void)ws_size;
  const float* inputs   = (const float*)d_in[0];
  const float* orig     = (const float*)d_in[1];
  const float* pfs      = (const float*)d_in[2];
  const float* ln2s     = (const float*)d_in[3];
  const float* post1    = (const float*)d_in[4];
  const float* post2    = (const float*)d_in[5];
  const float* router_w = (const float*)d_in[6];
  const float* e_wi0    = (const float*)d_in[7];
  const float* e_wi1    = (const float*)d_in[8];
  const float* e_wo     = (const float*)d_in[9];
  const float* s_wi0    = (const float*)d_in[10];
  const float* s_wi1    = (const float*)d_in[11];
  const float* s_wo     = (const float*)d_in[12];

  char* ws = (char*)d_ws;
  size_t o = 0;
  auto alloc = [&](size_t bytes) -> void* {
    void* p = ws + o;
    o += (bytes + 255) & ~(size_t)255;
    return p;
  };
  u16* s_wi_t  = (u16*)alloc((size_t)2 * FDIM * DIM * 2);        // [2][F,D]
  u16* s_wo_t  = (u16*)alloc((size_t)DIM * FDIM * 2);            // [D,F]
  u16* e_wi_t  = (u16*)alloc((size_t)2 * NEXP * MDIM * DIM * 2); // [2][E,M,D]
  u16* e_wo_t  = (u16*)alloc((size_t)NEXP * DIM * MDIM * 2);     // [E,D,M]
  u16* x_sh    = (u16*)alloc((size_t)T_TOK * DIM * 2);
  u16* routed  = (u16*)alloc((size_t)T_TOK * DIM * 2);
  float* probs = (float*)alloc((size_t)T_TOK * 8 * 4);
  int* eidx    = (int*)alloc((size_t)T_TOK * 2 * 4);
  float* ewt   = (float*)alloc((size_t)T_TOK * 2 * 4);
  int* pos     = (int*)alloc((size_t)T_TOK * 2 * 4);
  int* imeta   = (int*)alloc(256);           // [0..7] counts, [8..15] cursors
  int* poffset = (int*)alloc(64);
  int* n_tiles = (int*)alloc(64);
  int2* tdesc  = (int2*)alloc(MAXTILES * 8);
  int* ridx    = (int*)alloc((size_t)HROWS * 4);
  float* racc  = (float*)alloc((size_t)2 * T_TOK * DIM * 4);     // split-K partials
  u16* Hs      = (u16*)alloc((size_t)T_TOK * FDIM * 2);          // gated h (shared)
  u16* H       = (u16*)alloc((size_t)HROWS * MDIM * 2);          // gated h (routed)
  float* Hout  = (float*)alloc((size_t)2 * HROWS * DIM * 4);     // split-K partials

  int* counts = imeta;
  int* cursors = imeta + 8;

  hipMemsetAsync(imeta, 0, 64, stream);
  hipMemsetAsync(ridx, 0, (size_t)HROWS * 4, stream);

  // ---- weight transposes (f32 -> f16 B^T layouts), 4 launches ----
  transpose_cvt2<<<dim3(FDIM / 32, DIM / 32, 2), 256, 0, stream>>>(
      s_wi0, s_wi1, s_wi_t, DIM, FDIM, 1);
  transpose_cvt2<<<dim3(DIM / 32, FDIM / 32, 1), 256, 0, stream>>>(
      s_wo, s_wo, s_wo_t, FDIM, DIM, 1);
  transpose_cvt2<<<dim3(MDIM / 32, DIM / 32, 16), 256, 0, stream>>>(
      e_wi0, e_wi1, e_wi_t, DIM, MDIM, 8);
  transpose_cvt2<<<dim3(DIM / 32, MDIM / 32, 8), 256, 0, stream>>>(
      e_wo, e_wo, e_wo_t, MDIM, DIM, 8);

  router_kernel<<<T_TOK, 256, 0, stream>>>(orig, inputs, pfs, ln2s, router_w,
                                           routed, x_sh, eidx, ewt, probs);

  // ---- bucketing ----
  bucket_count<<<16, 256, 0, stream>>>(eidx, counts);
  setup_tiles<<<1, 64, 0, stream>>>(counts, poffset, tdesc, n_tiles);
  bucket_scatter<<<16, 256, 0, stream>>>(eidx, poffset, cursors, ridx, pos);

  // ---- merged in-GEMM (shared + routed gated) ----
  gemm_in<<<dim3(FDIM / 128, 32 + MAXTILES, 1), 256, 0, stream>>>(
      x_sh, s_wi_t, routed, e_wi_t, Hs, H, ridx, tdesc, n_tiles);

  // ---- merged out-GEMM (shared + routed, split-K=2) ----
  gemm_out2<<<dim3(DIM / 128, 32 + MAXTILES, 2), 256, 0, stream>>>(
      Hs, s_wo_t, racc, H, e_wo_t, Hout, tdesc, n_tiles);

  // ---- fused final norm + combine ----
  final_norm<<<T_TOK, 256, 0, stream>>>(racc, Hout, pos, ewt, post1, post2,
                                        (float*)d_out);

  lb_reduce<<<1, 256, 0, stream>>>(probs, counts, (float*)d_out + (size_t)T_TOK * DIM);
}